// Round 13
// baseline (218.571 us; speedup 1.0000x reference)
//
#include <hip/hip_runtime.h>

typedef unsigned short u16;
typedef unsigned int   u32;
typedef short bf16x8 __attribute__((ext_vector_type(8)));
typedef short bf16x4 __attribute__((ext_vector_type(4)));
typedef float f32x4  __attribute__((ext_vector_type(4)));

#define HIMG 56
#define WIMG 56
#define CH   128
#define NHEADS 4
#define WSZ  7
#define SSH  3
#define PP   10
#define HIDD 512
#define NWIN 49          // window tokens
#define NTOK 59          // P + NWIN
#define BWIN 2048        // B * NW
#define DH   32          // head dim
#define MWIN 120832      // BWIN * NTOK
#define MPIX 100352      // B * 56 * 56

__device__ __forceinline__ u16 f2b(float f) {
  u32 u = __float_as_uint(f);
  u += 0x7fffu + ((u >> 16) & 1u);
  return (u16)(u >> 16);
}
__device__ __forceinline__ u32 pack2(float a, float b) {
  return (u32)f2b(a) | ((u32)f2b(b) << 16);
}
__device__ __forceinline__ float bfh2f(u16 h) { return __uint_as_float((u32)h << 16); }
// fast exact-GELU: Abramowitz-Stegun 7.1.26 erf (max err 1.5e-7) — R7-proven
__device__ __forceinline__ float gelu(float x) {
  const float z = fabsf(x) * 0.70710678118654752f;
  const float t = 1.0f / (1.0f + 0.3275911f * z);
  const float p = t * (0.254829592f + t * (-0.284496736f + t * (1.421413741f +
                  t * (-1.453152027f + t * 1.061405429f))));
  const float erfz = copysignf(1.0f - p * __expf(-z * z), x);
  return 0.5f * x * (1.0f + erfz);
}

// ---------------------------------------------------------------------------
// Fold LoRA into effective weights, MFMA-fragment layouts (R8-proven).
// ---------------------------------------------------------------------------
__global__ void fuse_all_kernel(
    const float* __restrict__ qw,  const float* __restrict__ qa,  const float* __restrict__ qb,
    const float* __restrict__ pw,  const float* __restrict__ pa,  const float* __restrict__ pb,
    const float* __restrict__ f1w, const float* __restrict__ f1a, const float* __restrict__ f1b,
    const float* __restrict__ f2w, const float* __restrict__ f2a, const float* __restrict__ f2b2,
    u16* __restrict__ out)
{
  int idx = blockIdx.x * 256 + threadIdx.x;
  if (idx >= 196608) return;
  int n, k, Nc;
  const float *w, *la, *lb;
  if (idx < 49152) {                    // wqf
    const int li = idx;
    const int j = li & 7, lane = (li >> 3) & 63, kk = (li >> 9) & 3, c16 = li >> 11;
    n = c16 * 16 + (lane & 15);
    k = kk * 32 + (lane >> 4) * 8 + j;
    w = qw; la = qa; lb = qb; Nc = 384;
  } else if (idx < 65536) {             // wprojf
    const int li = idx - 49152;
    const int j = li & 7, lane = (li >> 3) & 63, kk = (li >> 9) & 3, c16 = li >> 11;
    n = c16 * 16 + (lane & 15);
    k = kk * 32 + (lane >> 4) * 8 + j;
    w = pw; la = pa; lb = pb; Nc = 128;
  } else if (idx < 131072) {            // w1f
    const int li = idx - 65536;
    const int j = li & 7, lane = (li >> 3) & 63, kk = (li >> 9) & 3, c16 = li >> 11;
    n = c16 * 16 + (lane & 15);
    k = kk * 32 + (lane >> 4) * 8 + j;
    w = f1w; la = f1a; lb = f1b; Nc = 512;
  } else {                              // w2f
    const int li = idx - 131072;
    const int j = li & 7, lane = (li >> 3) & 63, kk2 = (li >> 9) & 1, hb = (li >> 10) & 7, o16 = li >> 13;
    n = o16 * 16 + (lane & 15);
    k = hb * 64 + kk2 * 32 + (lane >> 4) * 8 + j;
    w = f2w; la = f2a; lb = f2b2; Nc = 128;
  }
  float s = w[k * Nc + n];
  #pragma unroll
  for (int r = 0; r < 4; ++r) s += la[k * 4 + r] * lb[r * Nc + n];
  out[idx] = f2b(s);
}

// ---------------------------------------------------------------------------
// Precompute bias+mask table bm[type][h][64][64] f32.
// ---------------------------------------------------------------------------
__global__ void bm_kernel(const float* __restrict__ rpb, float* __restrict__ bm)
{
  const int idx = blockIdx.x * 256 + threadIdx.x;   // 65536
  const int j = idx & 63, i = (idx >> 6) & 63, h = (idx >> 12) & 3, type = idx >> 14;
  float v = 0.f;
  if (i < 49) {
    if (j >= 59) v = -1e30f;
    else if (j >= PP) {
      const int jw = j - PP;
      const int ih = i / 7, iw = i - ih * 7, jh = jw / 7, jw2 = jw - jh * 7;
      v = rpb[((ih - jh + 6) * 13 + (iw - jw2 + 6)) * NHEADS + h];
      const int wh7 = type >> 1, ww7 = type & 1;
      const int mi = 3 * (wh7 ? (ih < 4 ? 1 : 2) : 0) + (ww7 ? (iw < 4 ? 1 : 2) : 0);
      const int mj = 3 * (wh7 ? (jh < 4 ? 1 : 2) : 0) + (ww7 ? (jw2 < 4 ? 1 : 2) : 0);
      if (mi != mj) v -= 100.f;
    }
  }
  bm[idx] = v;
}

// ---------------------------------------------------------------------------
// FUSED LN1 + qkv GEMM + window attention. One block = one window.
// Phase 0: gather x/prompt rows straight into A-frags with in-register LN1
//          (token group = lanes {lr, lr+16, lr+32, lr+48}; shfl_xor 16/32).
// Phases 1-2: R7-R11 proven qkv + attention math, unchanged.
// ---------------------------------------------------------------------------
#define QKS 136
#define VTS 72
#define PS  68
__global__ __launch_bounds__(256, 3) void qkv_attn_kernel(
    const float* __restrict__ x, const float* __restrict__ prompts,
    const float* __restrict__ n1g, const float* __restrict__ n1b,
    const u16* __restrict__ wqf, const float* __restrict__ qbias,
    const float* __restrict__ bm, u16* __restrict__ attn_out)
{
  __shared__ __align__(16) u16 smem[26624];   // 53248 B -> 3 blocks/CU
  u16* q_lds = smem;                // [64][QKS]
  u16* k_lds = smem + 64 * QKS;     // [64][QKS]
  u16* vt    = smem + 128 * QKS;    // [128][VTS]
  u16* p_lds = smem;                // overlay q+k: [4][64][PS]

  const int tid = threadIdx.x;
  const int wv = tid >> 6, lane = tid & 63;
  const int lr = lane & 15, lk = lane >> 4;
  const int b_ = blockIdx.x;
  const int bimg = b_ >> 6;
  const int wwin = b_ & 63;

  // ---- phase 0: LN1 gather -> af frags ----
  bf16x8 af[4][4];
  #pragma unroll
  for (int mt = 0; mt < 4; ++mt) {
    int n = mt * 16 + lr; if (n > 58) n = 58;
    const float* src;
    if (n < PP) {
      src = prompts + ((size_t)bimg * PP + n) * CH;
    } else {
      const int wi = n - PP;
      const int hr = (wwin >> 3) * WSZ + wi / WSZ;
      const int wc = (wwin & 7) * WSZ + wi % WSZ;
      const int hs = (hr + SSH) % HIMG;
      const int ws2 = (wc + SSH) % WIMG;
      src = x + ((size_t)bimg * (HIMG * WIMG) + hs * WIMG + ws2) * CH;
    }
    float4 va[8];
    #pragma unroll
    for (int kk = 0; kk < 4; ++kk) {
      va[kk * 2]     = *(const float4*)(src + kk * 32 + lk * 8);
      va[kk * 2 + 1] = *(const float4*)(src + kk * 32 + lk * 8 + 4);
    }
    float s = 0.f, s2 = 0.f;
    #pragma unroll
    for (int p = 0; p < 8; ++p) {
      s  += va[p].x + va[p].y + va[p].z + va[p].w;
      s2 += va[p].x * va[p].x + va[p].y * va[p].y + va[p].z * va[p].z + va[p].w * va[p].w;
    }
    s  += __shfl_xor(s, 16);  s2 += __shfl_xor(s2, 16);
    s  += __shfl_xor(s, 32);  s2 += __shfl_xor(s2, 32);
    const float mean = s * (1.0f / CH);
    const float inv  = rsqrtf(s2 * (1.0f / CH) - mean * mean + 1e-5f);
    const bool doln = (n >= PP);
    #pragma unroll
    for (int kk = 0; kk < 4; ++kk) {
      const int c0 = kk * 32 + lk * 8;
      const float4 g0 = *(const float4*)(n1g + c0);
      const float4 g1 = *(const float4*)(n1g + c0 + 4);
      const float4 bb0 = *(const float4*)(n1b + c0);
      const float4 bb1 = *(const float4*)(n1b + c0 + 4);
      const float4 A = va[kk * 2], B = va[kk * 2 + 1];
      float o0 = doln ? (A.x - mean) * inv * g0.x + bb0.x : A.x;
      float o1 = doln ? (A.y - mean) * inv * g0.y + bb0.y : A.y;
      float o2 = doln ? (A.z - mean) * inv * g0.z + bb0.z : A.z;
      float o3 = doln ? (A.w - mean) * inv * g0.w + bb0.w : A.w;
      float o4 = doln ? (B.x - mean) * inv * g1.x + bb1.x : B.x;
      float o5 = doln ? (B.y - mean) * inv * g1.y + bb1.y : B.y;
      float o6 = doln ? (B.z - mean) * inv * g1.z + bb1.z : B.z;
      float o7 = doln ? (B.w - mean) * inv * g1.w + bb1.w : B.w;
      uint4 pk;
      pk.x = pack2(o0, o1); pk.y = pack2(o2, o3);
      pk.z = pack2(o4, o5); pk.w = pack2(o6, o7);
      af[mt][kk] = *(bf16x8*)&pk;
    }
  }

  // ---- phase 1: qkv ----
  #pragma unroll
  for (int nf = 0; nf < 6; ++nf) {
    const int c = wv * 96 + nf * 16 + lr;
    const int sel = wv * 6 + nf;
    bf16x8 bw[4];
    #pragma unroll
    for (int kk = 0; kk < 4; ++kk)
      bw[kk] = *(const bf16x8*)(wqf + ((sel * 4 + kk) * 64 + lane) * 8);
    f32x4 a4[4];
    #pragma unroll
    for (int mt = 0; mt < 4; ++mt) a4[mt] = (f32x4){0.f, 0.f, 0.f, 0.f};
    #pragma unroll
    for (int kk = 0; kk < 4; ++kk)
      #pragma unroll
      for (int mt = 0; mt < 4; ++mt)
        a4[mt] = __builtin_amdgcn_mfma_f32_16x16x32_bf16(af[mt][kk], bw[kk], a4[mt], 0, 0, 0);
    const float bs = qbias[c];
    #pragma unroll
    for (int mt = 0; mt < 4; ++mt) {
      const int tok0 = mt * 16 + lk * 4;
      if (sel < 8) {
        #pragma unroll
        for (int rg = 0; rg < 4; ++rg)
          q_lds[(tok0 + rg) * QKS + c] = f2b(a4[mt][rg] + bs);
      } else if (sel < 16) {
        #pragma unroll
        for (int rg = 0; rg < 4; ++rg)
          k_lds[(tok0 + rg) * QKS + (c - 128)] = f2b(a4[mt][rg] + bs);
      } else {
        ushort4 pk = make_ushort4(f2b(a4[mt][0] + bs), f2b(a4[mt][1] + bs),
                                  f2b(a4[mt][2] + bs), f2b(a4[mt][3] + bs));
        *(ushort4*)&vt[(c - 256) * VTS + tok0] = pk;
      }
    }
  }
  __syncthreads();

  // ---- phase 2: attention, wave = head h ----
  const int h = wv;
  const int type = (((wwin >> 3) == 7) ? 2 : 0) + (((wwin & 7) == 7) ? 1 : 0);
  const float scale = 0.17677669529663687f;

  bf16x8 kf[4], qf[4];
  #pragma unroll
  for (int t4 = 0; t4 < 4; ++t4) {
    kf[t4] = *(const bf16x8*)&k_lds[(t4 * 16 + lr) * QKS + h * DH + lk * 8];
    int tq = PP + t4 * 16 + lr; if (tq > 63) tq = 63;
    qf[t4] = *(const bf16x8*)&q_lds[tq * QKS + h * DH + lk * 8];
  }
  f32x4 sacc[4][4];
  #pragma unroll
  for (int a = 0; a < 4; ++a)
    #pragma unroll
    for (int b = 0; b < 4; ++b)
      sacc[a][b] = (f32x4){0.f, 0.f, 0.f, 0.f};
  #pragma unroll
  for (int mtj = 0; mtj < 4; ++mtj)
    #pragma unroll
    for (int nti = 0; nti < 4; ++nti)
      sacc[mtj][nti] = __builtin_amdgcn_mfma_f32_16x16x32_bf16(kf[mtj], qf[nti], sacc[mtj][nti], 0, 0, 0);

  const float* bmh = bm + (size_t)(type * NHEADS + h) * 64 * 64;
  #pragma unroll
  for (int nti = 0; nti < 4; ++nti) {
    const int i = nti * 16 + lr;
    float sv[16];
    #pragma unroll
    for (int mtj = 0; mtj < 4; ++mtj) {
      const float4 bmv = *(const float4*)(bmh + i * 64 + mtj * 16 + lk * 4);
      sv[mtj * 4 + 0] = sacc[mtj][nti][0] * scale + bmv.x;
      sv[mtj * 4 + 1] = sacc[mtj][nti][1] * scale + bmv.y;
      sv[mtj * 4 + 2] = sacc[mtj][nti][2] * scale + bmv.z;
      sv[mtj * 4 + 3] = sacc[mtj][nti][3] * scale + bmv.w;
    }
    float mx = sv[0];
    #pragma unroll
    for (int q = 1; q < 16; ++q) mx = fmaxf(mx, sv[q]);
    mx = fmaxf(mx, __shfl_xor(mx, 16));
    mx = fmaxf(mx, __shfl_xor(mx, 32));
    float sum = 0.f;
    #pragma unroll
    for (int q = 0; q < 16; ++q) { sv[q] = __expf(sv[q] - mx); sum += sv[q]; }
    sum += __shfl_xor(sum, 16);
    sum += __shfl_xor(sum, 32);
    const float inv = 1.0f / sum;
    #pragma unroll
    for (int mtj = 0; mtj < 4; ++mtj) {
      sacc[mtj][nti][0] = sv[mtj * 4 + 0] * inv;
      sacc[mtj][nti][1] = sv[mtj * 4 + 1] * inv;
      sacc[mtj][nti][2] = sv[mtj * 4 + 2] * inv;
      sacc[mtj][nti][3] = sv[mtj * 4 + 3] * inv;
    }
  }
  __syncthreads();

  u16* ph = p_lds + h * 64 * PS;
  #pragma unroll
  for (int nti = 0; nti < 4; ++nti) {
    const int i = nti * 16 + lr;
    #pragma unroll
    for (int mtj = 0; mtj < 4; ++mtj) {
      const ushort4 pk = make_ushort4(f2b(sacc[mtj][nti][0]), f2b(sacc[mtj][nti][1]),
                                      f2b(sacc[mtj][nti][2]), f2b(sacc[mtj][nti][3]));
      *(ushort4*)&ph[i * PS + mtj * 16 + lk * 4] = pk;
    }
  }
  __syncthreads();

  f32x4 oacc[4][2];
  #pragma unroll
  for (int a = 0; a < 4; ++a) { oacc[a][0] = (f32x4){0,0,0,0}; oacc[a][1] = (f32x4){0,0,0,0}; }
  #pragma unroll
  for (int ks = 0; ks < 2; ++ks) {
    bf16x8 pa[4];
    #pragma unroll
    for (int mt = 0; mt < 4; ++mt) {
      const u16* pr = &ph[(mt * 16 + lr) * PS + ks * 32 + lk * 8];
      const bf16x4 lo = *(const bf16x4*)pr;
      const bf16x4 hi = *(const bf16x4*)(pr + 4);
      pa[mt] = __builtin_shufflevector(lo, hi, 0, 1, 2, 3, 4, 5, 6, 7);
    }
    bf16x8 bv[2];
    #pragma unroll
    for (int nd = 0; nd < 2; ++nd)
      bv[nd] = *(const bf16x8*)&vt[(h * DH + nd * 16 + lr) * VTS + ks * 32 + lk * 8];
    #pragma unroll
    for (int mt = 0; mt < 4; ++mt)
      #pragma unroll
      for (int nd = 0; nd < 2; ++nd)
        oacc[mt][nd] = __builtin_amdgcn_mfma_f32_16x16x32_bf16(pa[mt], bv[nd], oacc[mt][nd], 0, 0, 0);
  }

  #pragma unroll
  for (int mt = 0; mt < 4; ++mt)
    #pragma unroll
    for (int rg = 0; rg < 4; ++rg) {
      const int i = mt * 16 + lk * 4 + rg;
      ph[i * PS + lr]      = f2b(oacc[mt][0][rg]);
      ph[i * PS + 16 + lr] = f2b(oacc[mt][1][rg]);
    }
  __syncthreads();
  if (lane < NWIN) {
    const u16* src = &ph[lane * PS];
    u16* dst = attn_out + ((size_t)b_ * NWIN + lane) * CH + h * DH;
    #pragma unroll
    for (int c = 0; c < 8; ++c)
      *(uint2*)(dst + c * 4) = *(const uint2*)(src + c * 4);
  }
}

// ---------------------------------------------------------------------------
// FUSED proj + LN2 + MLP, 17.4 KB LDS -> 8 blocks/CU.
//  region1 [0,8704): sa[32][128] -> T16[32][136] (bf16 proj out) -> sm[32][128]
//  H [8704,17408): [2][32][68]
//  epilogue T32E[32][132] f32 overlays [0,16896) after H dies.
// x1 lives in 16 VGPRs throughout.
// ---------------------------------------------------------------------------
#define HS 68
__global__ __launch_bounds__(256, 8) void proj_mlp_kernel(
    const u16* __restrict__ ao, const u16* __restrict__ wprojf,
    const float* __restrict__ pbias, const float* __restrict__ x,
    const float* __restrict__ g2, const float* __restrict__ b2,
    const u16* __restrict__ w1f, const float* __restrict__ b1,
    const u16* __restrict__ w2f, const float* __restrict__ fc2b,
    float* __restrict__ outp)
{
  __shared__ __align__(16) char smem[17408];
  u16*   sa  = (u16*)smem;              // [32][128]
  u16*   T16 = (u16*)smem;              // [32][136]
  u16*   sm  = (u16*)smem;              // [32][128] swizzle16
  u16*   H   = (u16*)(smem + 8704);     // [2][32][HS]
  float* T32E = (float*)smem;           // [32][132] epilogue
  const int tid = threadIdx.x;
  const int wv = tid >> 6, lane = tid & 63;
  const int lr = lane & 15, lk = lane >> 4;
  const long rowbase = (long)blockIdx.x * 32;

  // ---- A: gather ao rows (inverse window map), swizzle16 source ----
  #pragma unroll
  for (int it = 0; it < 2; ++it) {
    const int c = it * 256 + tid;
    const int r = c >> 4, s = c & 15;
    const int k8 = s ^ (r & 15);
    const int pix = (int)rowbase + r;
    const int b  = pix / 3136;
    const int rem = pix - b * 3136;
    const int hf = rem / 56, wf = rem - hf * 56;
    int hs = hf + 53; if (hs >= 56) hs -= 56;
    int ws2 = wf + 53; if (ws2 >= 56) ws2 -= 56;
    const int w  = (hs / 7) * 8 + (ws2 / 7);
    const int wi = (hs % 7) * 7 + (ws2 % 7);
    const long arow = ((long)b * 64 + w) * NWIN + wi;
    __builtin_amdgcn_global_load_lds((const void*)(ao + arow * CH + k8 * 8),
                                     (void*)(sa + c * 8), 16, 0, 0);
  }
  __syncthreads();

  // ---- B: proj MFMA ----
  f32x4 pacc[2][2];
  #pragma unroll
  for (int a = 0; a < 2; ++a) { pacc[a][0] = (f32x4){0,0,0,0}; pacc[a][1] = (f32x4){0,0,0,0}; }
  #pragma unroll
  for (int kk = 0; kk < 4; ++kk) {
    bf16x8 af[2];
    #pragma unroll
    for (int mt = 0; mt < 2; ++mt) {
      const int r = mt * 16 + lr;
      af[mt] = *(const bf16x8*)(sa + r * 128 + (((kk * 4 + lk) ^ (r & 15)) << 3));
    }
    #pragma unroll
    for (int nf = 0; nf < 2; ++nf) {
      const int c16 = wv * 2 + nf;
      const bf16x8 bw = *(const bf16x8*)(wprojf + ((c16 * 4 + kk) * 64 + lane) * 8);
      #pragma unroll
      for (int mt = 0; mt < 2; ++mt)
        pacc[mt][nf] = __builtin_amdgcn_mfma_f32_16x16x32_bf16(af[mt], bw, pacc[mt][nf], 0, 0, 0);
    }
  }
  __syncthreads();   // sa reads done before T16 overlays

  // ---- C1: proj out + bias -> T16 (bf16) ----
  #pragma unroll
  for (int nf = 0; nf < 2; ++nf) {
    const int col = (wv * 2 + nf) * 16 + lr;
    const float bs = pbias[col];
    #pragma unroll
    for (int mt = 0; mt < 2; ++mt)
      #pragma unroll
      for (int j = 0; j < 4; ++j)
        T16[(mt * 16 + lk * 4 + j) * 136 + col] = f2b(pacc[mt][nf][j] + bs);
  }
  __syncthreads();

  // ---- C2a: read T16 + x -> x1 regs, LN2 stats, m values in regs ----
  const int rl = tid >> 3, q = tid & 7;      // 32 rows x 8 threads/row
  float4 xv[4];
  float sum = 0.f, sq = 0.f;
  {
    const float* xrow = x + (rowbase + rl) * CH;
    #pragma unroll
    for (int i = 0; i < 4; ++i) {
      const ushort4 hv = *(const ushort4*)&T16[rl * 136 + q * 4 + i * 32];
      const float4 xr = *(const float4*)(xrow + q * 4 + i * 32);
      float4 tv;
      tv.x = bfh2f(hv.x) + xr.x; tv.y = bfh2f(hv.y) + xr.y;
      tv.z = bfh2f(hv.z) + xr.z; tv.w = bfh2f(hv.w) + xr.w;
      xv[i] = tv;
      sum += tv.x + tv.y + tv.z + tv.w;
      sq  += tv.x * tv.x + tv.y * tv.y + tv.z * tv.z + tv.w * tv.w;
    }
  }
  sum += __shfl_xor(sum, 1); sq += __shfl_xor(sq, 1);
  sum += __shfl_xor(sum, 2); sq += __shfl_xor(sq, 2);
  sum += __shfl_xor(sum, 4); sq += __shfl_xor(sq, 4);
  uint2 mreg[4];
  {
    const float mean = sum * (1.0f / CH);
    const float inv  = rsqrtf(sq * (1.0f / CH) - mean * mean + 1e-5f);
    #pragma unroll
    for (int i = 0; i < 4; ++i) {
      const int col0 = q * 4 + i * 32;
      const float4 gg = *(const float4*)(g2 + col0);
      const float4 bb = *(const float4*)(b2 + col0);
      mreg[i].x = pack2((xv[i].x - mean) * inv * gg.x + bb.x,
                        (xv[i].y - mean) * inv * gg.y + bb.y);
      mreg[i].y = pack2((xv[i].z - mean) * inv * gg.z + bb.z,
                        (xv[i].w - mean) * inv * gg.w + bb.w);
    }
  }
  __syncthreads();   // all T16 reads done before sm overlays

  // ---- C2b: write m -> sm (swizzle16) ----
  #pragma unroll
  for (int i = 0; i < 4; ++i) {
    const int col0 = q * 4 + i * 32;
    const int slot = col0 >> 3;
    const int off = rl * 128 + ((slot ^ (rl & 15)) << 3) + (col0 & 7);
    *(uint2*)&sm[off] = mreg[i];
  }
  __syncthreads();

  // ---- D: MLP (R10/R11-proven) ----
  f32x4 oad[2][2];
  #pragma unroll
  for (int a = 0; a < 2; ++a) { oad[a][0] = (f32x4){0,0,0,0}; oad[a][1] = (f32x4){0,0,0,0}; }

  auto stage1 = [&](int hb, u16* Hbuf) {
    f32x4 c1[2];
    c1[0] = (f32x4){0.f, 0.f, 0.f, 0.f};
    c1[1] = (f32x4){0.f, 0.f, 0.f, 0.f};
    #pragma unroll
    for (int kk = 0; kk < 4; ++kk) {
      const int c16 = hb * 4 + wv;
      const bf16x8 a1 = *(const bf16x8*)(w1f + ((c16 * 4 + kk) * 64 + lane) * 8);
      bf16x8 bmv[2];
      #pragma unroll
      for (int nt = 0; nt < 2; ++nt) {
        const int r = nt * 16 + lr;
        bmv[nt] = *(const bf16x8*)(sm + r * 128 + (((kk * 4 + lk) ^ (r & 15)) << 3));
      }
      c1[0] = __builtin_amdgcn_mfma_f32_16x16x32_bf16(a1, bmv[0], c1[0], 0, 0, 0);
      c1[1] = __builtin_amdgcn_mfma_f32_16x16x32_bf16(a1, bmv[1], c1[1], 0, 0, 0);
    }
    const int hc0 = wv * 16 + lk * 4;
    const float4 bs = *(const float4*)(b1 + hb * 64 + hc0);
    #pragma unroll
    for (int nt = 0; nt < 2; ++nt) {
      const int tok = nt * 16 + lr;
      const ushort4 pk = make_ushort4(
          f2b(gelu(c1[nt][0] + bs.x)), f2b(gelu(c1[nt][1] + bs.y)),
          f2b(gelu(c1[nt][2] + bs.z)), f2b(gelu(c1[nt][3] + bs.w)));
      *(ushort4*)&Hbuf[tok * HS + hc0] = pk;
    }
  };

  auto stage2 = [&](int hb, const u16* Hbuf) {
    #pragma unroll
    for (int kk2 = 0; kk2 < 2; ++kk2) {
      bf16x8 a2[2];
      #pragma unroll
      for (int mt = 0; mt < 2; ++mt) {
        const u16* pr = &Hbuf[(mt * 16 + lr) * HS + kk2 * 32 + lk * 8];
        const bf16x4 lo = *(const bf16x4*)pr;
        const bf16x4 hi = *(const bf16x4*)(pr + 4);
        a2[mt] = __builtin_shufflevector(lo, hi, 0, 1, 2, 3, 4, 5, 6, 7);
      }
      #pragma unroll
      for (int nf2 = 0; nf2 < 2; ++nf2) {
        const int o16 = wv * 2 + nf2;
        const bf16x8 bw = *(const bf16x8*)(w2f + (((o16 * 8 + hb) * 2 + kk2) * 64 + lane) * 8);
        #pragma unroll
        for (int mt = 0; mt < 2; ++mt)
          oad[mt][nf2] = __builtin_amdgcn_mfma_f32_16x16x32_bf16(a2[mt], bw, oad[mt][nf2], 0, 0, 0);
      }
    }
  };

  u16* H0 = H;
  u16* H1 = H + 32 * HS;
  stage1(0, H0);
  __syncthreads();
  for (int hb = 0; hb < 8; ++hb) {
    u16* cur = (hb & 1) ? H1 : H0;
    u16* nxt = (hb & 1) ? H0 : H1;
    if (hb < 7) stage1(hb + 1, nxt);
    stage2(hb, cur);
    __syncthreads();
  }

  // ---- E: transpose + fc2 bias, then + x1 regs -> out ----
  #pragma unroll
  for (int nf2 = 0; nf2 < 2; ++nf2) {
    const int col = wv * 32 + nf2 * 16 + lr;
    const float bs = fc2b[col];
    #pragma unroll
    for (int mt = 0; mt < 2; ++mt)
      #pragma unroll
      for (int j = 0; j < 4; ++j)
        T32E[(mt * 16 + lk * 4 + j) * 132 + col] = oad[mt][nf2][j] + bs;
  }
  __syncthreads();
  {
    float* orow = outp + (rowbase + rl) * CH;
    #pragma unroll
    for (int i = 0; i < 4; ++i) {
      float4 v = *(const float4*)&T32E[rl * 132 + q * 4 + i * 32];
      v.x += xv[i].x; v.y += xv[i].y; v.z += xv[i].z; v.w += xv[i].w;
      *(float4*)(orow + q * 4 + i * 32) = v;
    }
  }
}

// ---------------------------------------------------------------------------
extern "C" void kernel_launch(void* const* d_in, const int* in_sizes, int n_in,
                              void* d_out, int out_size, void* d_ws, size_t ws_size,
                              hipStream_t stream)
{
  const float* x       = (const float*)d_in[0];
  const float* prompts = (const float*)d_in[1];
  const float* n1g     = (const float*)d_in[2];
  const float* n1b     = (const float*)d_in[3];
  const float* qkv_w   = (const float*)d_in[4];
  const float* qkv_b   = (const float*)d_in[5];
  const float* qkv_la  = (const float*)d_in[6];
  const float* qkv_lb  = (const float*)d_in[7];
  const float* rpb     = (const float*)d_in[8];
  const float* proj_w  = (const float*)d_in[9];
  const float* proj_b  = (const float*)d_in[10];
  const float* proj_la = (const float*)d_in[11];
  const float* proj_lb = (const float*)d_in[12];
  const float* n2g     = (const float*)d_in[13];
  const float* n2b     = (const float*)d_in[14];
  const float* fc1_w   = (const float*)d_in[15];
  const float* fc1_b   = (const float*)d_in[16];
  const float* fc1_la  = (const float*)d_in[17];
  const float* fc1_lb  = (const float*)d_in[18];
  const float* fc2_w   = (const float*)d_in[19];
  const float* fc2_b   = (const float*)d_in[20];
  const float* fc2_la  = (const float*)d_in[21];
  const float* fc2_lb  = (const float*)d_in[22];

  // workspace: [wqf|wprojf|w1f|w2f = 196608 u16] [bm 65536 f32] | aobuf
  char* ws = (char*)d_ws;
  u16* wT     = (u16*)ws;
  u16* wqf    = wT;
  u16* wprojf = wT + 49152;
  u16* w1f    = wT + 65536;
  u16* w2f    = wT + 131072;
  float* bm   = (float*)(ws + 393216);
  u16* aobuf  = (u16*)(ws + 393216 + 262144);

  fuse_all_kernel<<<768, 256, 0, stream>>>(
      qkv_w, qkv_la, qkv_lb, proj_w, proj_la, proj_lb,
      fc1_w, fc1_la, fc1_lb, fc2_w, fc2_la, fc2_lb, wT);

  bm_kernel<<<256, 256, 0, stream>>>(rpb, bm);

  qkv_attn_kernel<<<BWIN, 256, 0, stream>>>(
      x, prompts, n1g, n1b, wqf, qkv_b, bm, aobuf);

  proj_mlp_kernel<<<MPIX / 32, 256, 0, stream>>>(
      aobuf, wprojf, proj_b, x, n2g, n2b,
      w1f, fc1_b, w2f, fc2_b, (float*)d_out);
}

// Round 14
// 167.810 us; speedup vs baseline: 1.3025x; 1.3025x over previous
//
#include <hip/hip_runtime.h>

typedef unsigned short u16;
typedef unsigned int   u32;
typedef short bf16x8 __attribute__((ext_vector_type(8)));
typedef short bf16x4 __attribute__((ext_vector_type(4)));
typedef float f32x4  __attribute__((ext_vector_type(4)));

#define HIMG 56
#define WIMG 56
#define CH   128
#define NHEADS 4
#define WSZ  7
#define SSH  3
#define PP   10
#define HIDD 512
#define NWIN 49          // window tokens
#define NTOK 59          // P + NWIN
#define BWIN 2048        // B * NW
#define DH   32          // head dim
#define MWIN 120832      // BWIN * NTOK
#define MPIX 100352      // B * 56 * 56

__device__ __forceinline__ u16 f2b(float f) {
  u32 u = __float_as_uint(f);
  u += 0x7fffu + ((u >> 16) & 1u);
  return (u16)(u >> 16);
}
__device__ __forceinline__ u32 pack2(float a, float b) {
  return (u32)f2b(a) | ((u32)f2b(b) << 16);
}
__device__ __forceinline__ float bfh2f(u16 h) { return __uint_as_float((u32)h << 16); }
// fast exact-GELU: Abramowitz-Stegun 7.1.26 erf (max err 1.5e-7) — R7-proven
__device__ __forceinline__ float gelu(float x) {
  const float z = fabsf(x) * 0.70710678118654752f;
  const float t = 1.0f / (1.0f + 0.3275911f * z);
  const float p = t * (0.254829592f + t * (-0.284496736f + t * (1.421413741f +
                  t * (-1.453152027f + t * 1.061405429f))));
  const float erfz = copysignf(1.0f - p * __expf(-z * z), x);
  return 0.5f * x * (1.0f + erfz);
}

// ---------------------------------------------------------------------------
// Fold LoRA into effective weights, MFMA-fragment layouts (R8-proven).
// ---------------------------------------------------------------------------
__global__ void fuse_all_kernel(
    const float* __restrict__ qw,  const float* __restrict__ qa,  const float* __restrict__ qb,
    const float* __restrict__ pw,  const float* __restrict__ pa,  const float* __restrict__ pb,
    const float* __restrict__ f1w, const float* __restrict__ f1a, const float* __restrict__ f1b,
    const float* __restrict__ f2w, const float* __restrict__ f2a, const float* __restrict__ f2b2,
    u16* __restrict__ out)
{
  int idx = blockIdx.x * 256 + threadIdx.x;
  if (idx >= 196608) return;
  int n, k, Nc;
  const float *w, *la, *lb;
  if (idx < 49152) {                    // wqf
    const int li = idx;
    const int j = li & 7, lane = (li >> 3) & 63, kk = (li >> 9) & 3, c16 = li >> 11;
    n = c16 * 16 + (lane & 15);
    k = kk * 32 + (lane >> 4) * 8 + j;
    w = qw; la = qa; lb = qb; Nc = 384;
  } else if (idx < 65536) {             // wprojf
    const int li = idx - 49152;
    const int j = li & 7, lane = (li >> 3) & 63, kk = (li >> 9) & 3, c16 = li >> 11;
    n = c16 * 16 + (lane & 15);
    k = kk * 32 + (lane >> 4) * 8 + j;
    w = pw; la = pa; lb = pb; Nc = 128;
  } else if (idx < 131072) {            // w1f
    const int li = idx - 65536;
    const int j = li & 7, lane = (li >> 3) & 63, kk = (li >> 9) & 3, c16 = li >> 11;
    n = c16 * 16 + (lane & 15);
    k = kk * 32 + (lane >> 4) * 8 + j;
    w = f1w; la = f1a; lb = f1b; Nc = 512;
  } else {                              // w2f
    const int li = idx - 131072;
    const int j = li & 7, lane = (li >> 3) & 63, kk2 = (li >> 9) & 1, hb = (li >> 10) & 7, o16 = li >> 13;
    n = o16 * 16 + (lane & 15);
    k = hb * 64 + kk2 * 32 + (lane >> 4) * 8 + j;
    w = f2w; la = f2a; lb = f2b2; Nc = 128;
  }
  float s = w[k * Nc + n];
  #pragma unroll
  for (int r = 0; r < 4; ++r) s += la[k * 4 + r] * lb[r * Nc + n];
  out[idx] = f2b(s);
}

// ---------------------------------------------------------------------------
// Precompute bias+mask table bm[type][h][64][64] f32.
// ---------------------------------------------------------------------------
__global__ void bm_kernel(const float* __restrict__ rpb, float* __restrict__ bm)
{
  const int idx = blockIdx.x * 256 + threadIdx.x;   // 65536
  const int j = idx & 63, i = (idx >> 6) & 63, h = (idx >> 12) & 3, type = idx >> 14;
  float v = 0.f;
  if (i < 49) {
    if (j >= 59) v = -1e30f;
    else if (j >= PP) {
      const int jw = j - PP;
      const int ih = i / 7, iw = i - ih * 7, jh = jw / 7, jw2 = jw - jh * 7;
      v = rpb[((ih - jh + 6) * 13 + (iw - jw2 + 6)) * NHEADS + h];
      const int wh7 = type >> 1, ww7 = type & 1;
      const int mi = 3 * (wh7 ? (ih < 4 ? 1 : 2) : 0) + (ww7 ? (iw < 4 ? 1 : 2) : 0);
      const int mj = 3 * (wh7 ? (jh < 4 ? 1 : 2) : 0) + (ww7 ? (jw2 < 4 ? 1 : 2) : 0);
      if (mi != mj) v -= 100.f;
    }
  }
  bm[idx] = v;
}

// ---------------------------------------------------------------------------
// LN1 + roll(-3,-3) + window partition + prompt concat -> t (MWIN x 128) bf16
// (R3-R11 proven; coalesced 512B/token, one wave per token.)
// ---------------------------------------------------------------------------
__global__ __launch_bounds__(256) void ln1_gather_kernel(
    const float* __restrict__ x, const float* __restrict__ prompts,
    const float* __restrict__ g, const float* __restrict__ bb,
    u16* __restrict__ t)
{
  const int tok  = blockIdx.x * 4 + (threadIdx.x >> 6);
  const int lane = threadIdx.x & 63;
  const int b_ = tok / NTOK, n = tok - b_ * NTOK;
  u32* dst = (u32*)(t + (size_t)tok * CH) + lane;
  if (n < PP) {
    const int b = b_ >> 6;
    const float2 v = *(const float2*)(prompts + ((size_t)b * PP + n) * CH + lane * 2);
    *dst = pack2(v.x, v.y);
    return;
  }
  const int w  = b_ & 63;
  const int wi = n - PP;
  const int hr = (w >> 3) * WSZ + wi / WSZ;
  const int wc = (w & 7) * WSZ + wi % WSZ;
  const int hs  = (hr + SSH) % HIMG;
  const int ws2 = (wc + SSH) % WIMG;
  const float2 v = *(const float2*)(x + ((size_t)(b_ >> 6) * (HIMG * WIMG) + hs * WIMG + ws2) * CH + lane * 2);
  float s = v.x + v.y, s2 = v.x * v.x + v.y * v.y;
  #pragma unroll
  for (int o = 32; o > 0; o >>= 1) { s += __shfl_xor(s, o); s2 += __shfl_xor(s2, o); }
  const float mean = s * (1.0f / CH);
  const float inv  = rsqrtf(s2 * (1.0f / CH) - mean * mean + 1e-5f);
  const float2 gg = *(const float2*)(g  + lane * 2);
  const float2 bv = *(const float2*)(bb + lane * 2);
  *dst = pack2((v.x - mean) * inv * gg.x + bv.x, (v.y - mean) * inv * gg.y + bv.y);
}

// ---------------------------------------------------------------------------
// FUSED qkv GEMM + window attention (R7-R11 proven, reads bf16 t rows).
// ---------------------------------------------------------------------------
#define QKS 136
#define VTS 72
#define PS  68
__global__ __launch_bounds__(256, 3) void qkv_attn_kernel(
    const u16* __restrict__ t, const u16* __restrict__ wqf,
    const float* __restrict__ qbias, const float* __restrict__ bm,
    u16* __restrict__ attn_out)
{
  __shared__ __align__(16) u16 smem[26624];   // 53248 B -> 3 blocks/CU
  u16* q_lds = smem;                // [64][QKS]
  u16* k_lds = smem + 64 * QKS;     // [64][QKS]
  u16* vt    = smem + 128 * QKS;    // [128][VTS]
  u16* p_lds = smem;                // overlay q+k: [4][64][PS]

  const int tid = threadIdx.x;
  const int wv = tid >> 6, lane = tid & 63;
  const int lr = lane & 15, lk = lane >> 4;
  const int b_ = blockIdx.x;
  const long tbase = (long)b_ * NTOK;

  // ---- phase 1: qkv ----
  bf16x8 af[4][4];
  #pragma unroll
  for (int mt = 0; mt < 4; ++mt) {
    int tok = mt * 16 + lr; if (tok > 58) tok = 58;
    #pragma unroll
    for (int kk = 0; kk < 4; ++kk)
      af[mt][kk] = *(const bf16x8*)(t + (tbase + tok) * CH + kk * 32 + lk * 8);
  }
  #pragma unroll
  for (int nf = 0; nf < 6; ++nf) {
    const int c = wv * 96 + nf * 16 + lr;
    const int sel = wv * 6 + nf;
    bf16x8 bw[4];
    #pragma unroll
    for (int kk = 0; kk < 4; ++kk)
      bw[kk] = *(const bf16x8*)(wqf + ((sel * 4 + kk) * 64 + lane) * 8);
    f32x4 a4[4];
    #pragma unroll
    for (int mt = 0; mt < 4; ++mt) a4[mt] = (f32x4){0.f, 0.f, 0.f, 0.f};
    #pragma unroll
    for (int kk = 0; kk < 4; ++kk)
      #pragma unroll
      for (int mt = 0; mt < 4; ++mt)
        a4[mt] = __builtin_amdgcn_mfma_f32_16x16x32_bf16(af[mt][kk], bw[kk], a4[mt], 0, 0, 0);
    const float bs = qbias[c];
    #pragma unroll
    for (int mt = 0; mt < 4; ++mt) {
      const int tok0 = mt * 16 + lk * 4;
      if (sel < 8) {
        #pragma unroll
        for (int rg = 0; rg < 4; ++rg)
          q_lds[(tok0 + rg) * QKS + c] = f2b(a4[mt][rg] + bs);
      } else if (sel < 16) {
        #pragma unroll
        for (int rg = 0; rg < 4; ++rg)
          k_lds[(tok0 + rg) * QKS + (c - 128)] = f2b(a4[mt][rg] + bs);
      } else {
        ushort4 pk = make_ushort4(f2b(a4[mt][0] + bs), f2b(a4[mt][1] + bs),
                                  f2b(a4[mt][2] + bs), f2b(a4[mt][3] + bs));
        *(ushort4*)&vt[(c - 256) * VTS + tok0] = pk;
      }
    }
  }
  __syncthreads();

  // ---- phase 2: attention, wave = head h ----
  const int h = wv;
  const int w = b_ & 63;
  const int type = (((w >> 3) == 7) ? 2 : 0) + (((w & 7) == 7) ? 1 : 0);
  const float scale = 0.17677669529663687f;

  bf16x8 kf[4], qf[4];
  #pragma unroll
  for (int t4 = 0; t4 < 4; ++t4) {
    kf[t4] = *(const bf16x8*)&k_lds[(t4 * 16 + lr) * QKS + h * DH + lk * 8];
    int tq = PP + t4 * 16 + lr; if (tq > 63) tq = 63;
    qf[t4] = *(const bf16x8*)&q_lds[tq * QKS + h * DH + lk * 8];
  }
  f32x4 sacc[4][4];
  #pragma unroll
  for (int a = 0; a < 4; ++a)
    #pragma unroll
    for (int b = 0; b < 4; ++b)
      sacc[a][b] = (f32x4){0.f, 0.f, 0.f, 0.f};
  #pragma unroll
  for (int mtj = 0; mtj < 4; ++mtj)
    #pragma unroll
    for (int nti = 0; nti < 4; ++nti)
      sacc[mtj][nti] = __builtin_amdgcn_mfma_f32_16x16x32_bf16(kf[mtj], qf[nti], sacc[mtj][nti], 0, 0, 0);

  const float* bmh = bm + (size_t)(type * NHEADS + h) * 64 * 64;
  #pragma unroll
  for (int nti = 0; nti < 4; ++nti) {
    const int i = nti * 16 + lr;
    float sv[16];
    #pragma unroll
    for (int mtj = 0; mtj < 4; ++mtj) {
      const float4 bmv = *(const float4*)(bmh + i * 64 + mtj * 16 + lk * 4);
      sv[mtj * 4 + 0] = sacc[mtj][nti][0] * scale + bmv.x;
      sv[mtj * 4 + 1] = sacc[mtj][nti][1] * scale + bmv.y;
      sv[mtj * 4 + 2] = sacc[mtj][nti][2] * scale + bmv.z;
      sv[mtj * 4 + 3] = sacc[mtj][nti][3] * scale + bmv.w;
    }
    float mx = sv[0];
    #pragma unroll
    for (int q = 1; q < 16; ++q) mx = fmaxf(mx, sv[q]);
    mx = fmaxf(mx, __shfl_xor(mx, 16));
    mx = fmaxf(mx, __shfl_xor(mx, 32));
    float sum = 0.f;
    #pragma unroll
    for (int q = 0; q < 16; ++q) { sv[q] = __expf(sv[q] - mx); sum += sv[q]; }
    sum += __shfl_xor(sum, 16);
    sum += __shfl_xor(sum, 32);
    const float inv = 1.0f / sum;
    #pragma unroll
    for (int mtj = 0; mtj < 4; ++mtj) {
      sacc[mtj][nti][0] = sv[mtj * 4 + 0] * inv;
      sacc[mtj][nti][1] = sv[mtj * 4 + 1] * inv;
      sacc[mtj][nti][2] = sv[mtj * 4 + 2] * inv;
      sacc[mtj][nti][3] = sv[mtj * 4 + 3] * inv;
    }
  }
  __syncthreads();

  u16* ph = p_lds + h * 64 * PS;
  #pragma unroll
  for (int nti = 0; nti < 4; ++nti) {
    const int i = nti * 16 + lr;
    #pragma unroll
    for (int mtj = 0; mtj < 4; ++mtj) {
      const ushort4 pk = make_ushort4(f2b(sacc[mtj][nti][0]), f2b(sacc[mtj][nti][1]),
                                      f2b(sacc[mtj][nti][2]), f2b(sacc[mtj][nti][3]));
      *(ushort4*)&ph[i * PS + mtj * 16 + lk * 4] = pk;
    }
  }
  __syncthreads();

  f32x4 oacc[4][2];
  #pragma unroll
  for (int a = 0; a < 4; ++a) { oacc[a][0] = (f32x4){0,0,0,0}; oacc[a][1] = (f32x4){0,0,0,0}; }
  #pragma unroll
  for (int ks = 0; ks < 2; ++ks) {
    bf16x8 pa[4];
    #pragma unroll
    for (int mt = 0; mt < 4; ++mt) {
      const u16* pr = &ph[(mt * 16 + lr) * PS + ks * 32 + lk * 8];
      const bf16x4 lo = *(const bf16x4*)pr;
      const bf16x4 hi = *(const bf16x4*)(pr + 4);
      pa[mt] = __builtin_shufflevector(lo, hi, 0, 1, 2, 3, 4, 5, 6, 7);
    }
    bf16x8 bv[2];
    #pragma unroll
    for (int nd = 0; nd < 2; ++nd)
      bv[nd] = *(const bf16x8*)&vt[(h * DH + nd * 16 + lr) * VTS + ks * 32 + lk * 8];
    #pragma unroll
    for (int mt = 0; mt < 4; ++mt)
      #pragma unroll
      for (int nd = 0; nd < 2; ++nd)
        oacc[mt][nd] = __builtin_amdgcn_mfma_f32_16x16x32_bf16(pa[mt], bv[nd], oacc[mt][nd], 0, 0, 0);
  }

  #pragma unroll
  for (int mt = 0; mt < 4; ++mt)
    #pragma unroll
    for (int rg = 0; rg < 4; ++rg) {
      const int i = mt * 16 + lk * 4 + rg;
      ph[i * PS + lr]      = f2b(oacc[mt][0][rg]);
      ph[i * PS + 16 + lr] = f2b(oacc[mt][1][rg]);
    }
  __syncthreads();
  if (lane < NWIN) {
    const u16* src = &ph[lane * PS];
    u16* dst = attn_out + ((size_t)b_ * NWIN + lane) * CH + h * DH;
    #pragma unroll
    for (int c = 0; c < 8; ++c)
      *(uint2*)(dst + c * 4) = *(const uint2*)(src + c * 4);
  }
}

// ---------------------------------------------------------------------------
// FUSED proj + LN2 + MLP, 17.4 KB LDS -> 8 blocks/CU (R13-proven, ~60 µs).
// ---------------------------------------------------------------------------
#define HS 68
__global__ __launch_bounds__(256, 8) void proj_mlp_kernel(
    const u16* __restrict__ ao, const u16* __restrict__ wprojf,
    const float* __restrict__ pbias, const float* __restrict__ x,
    const float* __restrict__ g2, const float* __restrict__ b2,
    const u16* __restrict__ w1f, const float* __restrict__ b1,
    const u16* __restrict__ w2f, const float* __restrict__ fc2b,
    float* __restrict__ outp)
{
  __shared__ __align__(16) char smem[17408];
  u16*   sa  = (u16*)smem;              // [32][128]
  u16*   T16 = (u16*)smem;              // [32][136]
  u16*   sm  = (u16*)smem;              // [32][128] swizzle16
  u16*   H   = (u16*)(smem + 8704);     // [2][32][HS]
  float* T32E = (float*)smem;           // [32][132] epilogue
  const int tid = threadIdx.x;
  const int wv = tid >> 6, lane = tid & 63;
  const int lr = lane & 15, lk = lane >> 4;
  const long rowbase = (long)blockIdx.x * 32;

  // ---- A: gather ao rows (inverse window map), swizzle16 source ----
  #pragma unroll
  for (int it = 0; it < 2; ++it) {
    const int c = it * 256 + tid;
    const int r = c >> 4, s = c & 15;
    const int k8 = s ^ (r & 15);
    const int pix = (int)rowbase + r;
    const int b  = pix / 3136;
    const int rem = pix - b * 3136;
    const int hf = rem / 56, wf = rem - hf * 56;
    int hs = hf + 53; if (hs >= 56) hs -= 56;
    int ws2 = wf + 53; if (ws2 >= 56) ws2 -= 56;
    const int w  = (hs / 7) * 8 + (ws2 / 7);
    const int wi = (hs % 7) * 7 + (ws2 % 7);
    const long arow = ((long)b * 64 + w) * NWIN + wi;
    __builtin_amdgcn_global_load_lds((const void*)(ao + arow * CH + k8 * 8),
                                     (void*)(sa + c * 8), 16, 0, 0);
  }
  __syncthreads();

  // ---- B: proj MFMA ----
  f32x4 pacc[2][2];
  #pragma unroll
  for (int a = 0; a < 2; ++a) { pacc[a][0] = (f32x4){0,0,0,0}; pacc[a][1] = (f32x4){0,0,0,0}; }
  #pragma unroll
  for (int kk = 0; kk < 4; ++kk) {
    bf16x8 af[2];
    #pragma unroll
    for (int mt = 0; mt < 2; ++mt) {
      const int r = mt * 16 + lr;
      af[mt] = *(const bf16x8*)(sa + r * 128 + (((kk * 4 + lk) ^ (r & 15)) << 3));
    }
    #pragma unroll
    for (int nf = 0; nf < 2; ++nf) {
      const int c16 = wv * 2 + nf;
      const bf16x8 bw = *(const bf16x8*)(wprojf + ((c16 * 4 + kk) * 64 + lane) * 8);
      #pragma unroll
      for (int mt = 0; mt < 2; ++mt)
        pacc[mt][nf] = __builtin_amdgcn_mfma_f32_16x16x32_bf16(af[mt], bw, pacc[mt][nf], 0, 0, 0);
    }
  }
  __syncthreads();   // sa reads done before T16 overlays

  // ---- C1: proj out + bias -> T16 (bf16) ----
  #pragma unroll
  for (int nf = 0; nf < 2; ++nf) {
    const int col = (wv * 2 + nf) * 16 + lr;
    const float bs = pbias[col];
    #pragma unroll
    for (int mt = 0; mt < 2; ++mt)
      #pragma unroll
      for (int j = 0; j < 4; ++j)
        T16[(mt * 16 + lk * 4 + j) * 136 + col] = f2b(pacc[mt][nf][j] + bs);
  }
  __syncthreads();

  // ---- C2a: read T16 + x -> x1 regs, LN2 stats ----
  const int rl = tid >> 3, q = tid & 7;      // 32 rows x 8 threads/row
  float4 xv[4];
  float sum = 0.f, sq = 0.f;
  {
    const float* xrow = x + (rowbase + rl) * CH;
    #pragma unroll
    for (int i = 0; i < 4; ++i) {
      const ushort4 hv = *(const ushort4*)&T16[rl * 136 + q * 4 + i * 32];
      const float4 xr = *(const float4*)(xrow + q * 4 + i * 32);
      float4 tv;
      tv.x = bfh2f(hv.x) + xr.x; tv.y = bfh2f(hv.y) + xr.y;
      tv.z = bfh2f(hv.z) + xr.z; tv.w = bfh2f(hv.w) + xr.w;
      xv[i] = tv;
      sum += tv.x + tv.y + tv.z + tv.w;
      sq  += tv.x * tv.x + tv.y * tv.y + tv.z * tv.z + tv.w * tv.w;
    }
  }
  sum += __shfl_xor(sum, 1); sq += __shfl_xor(sq, 1);
  sum += __shfl_xor(sum, 2); sq += __shfl_xor(sq, 2);
  sum += __shfl_xor(sum, 4); sq += __shfl_xor(sq, 4);
  uint2 mreg[4];
  {
    const float mean = sum * (1.0f / CH);
    const float inv  = rsqrtf(sq * (1.0f / CH) - mean * mean + 1e-5f);
    #pragma unroll
    for (int i = 0; i < 4; ++i) {
      const int col0 = q * 4 + i * 32;
      const float4 gg = *(const float4*)(g2 + col0);
      const float4 bb = *(const float4*)(b2 + col0);
      mreg[i].x = pack2((xv[i].x - mean) * inv * gg.x + bb.x,
                        (xv[i].y - mean) * inv * gg.y + bb.y);
      mreg[i].y = pack2((xv[i].z - mean) * inv * gg.z + bb.z,
                        (xv[i].w - mean) * inv * gg.w + bb.w);
    }
  }
  __syncthreads();   // all T16 reads done before sm overlays

  // ---- C2b: write m -> sm (swizzle16) ----
  #pragma unroll
  for (int i = 0; i < 4; ++i) {
    const int col0 = q * 4 + i * 32;
    const int slot = col0 >> 3;
    const int off = rl * 128 + ((slot ^ (rl & 15)) << 3) + (col0 & 7);
    *(uint2*)&sm[off] = mreg[i];
  }
  __syncthreads();

  // ---- D: MLP (R10/R13-proven) ----
  f32x4 oad[2][2];
  #pragma unroll
  for (int a = 0; a < 2; ++a) { oad[a][0] = (f32x4){0,0,0,0}; oad[a][1] = (f32x4){0,0,0,0}; }

  auto stage1 = [&](int hb, u16* Hbuf) {
    f32x4 c1[2];
    c1[0] = (f32x4){0.f, 0.f, 0.f, 0.f};
    c1[1] = (f32x4){0.f, 0.f, 0.f, 0.f};
    #pragma unroll
    for (int kk = 0; kk < 4; ++kk) {
      const int c16 = hb * 4 + wv;
      const bf16x8 a1 = *(const bf16x8*)(w1f + ((c16 * 4 + kk) * 64 + lane) * 8);
      bf16x8 bmv[2];
      #pragma unroll
      for (int nt = 0; nt < 2; ++nt) {
        const int r = nt * 16 + lr;
        bmv[nt] = *(const bf16x8*)(sm + r * 128 + (((kk * 4 + lk) ^ (r & 15)) << 3));
      }
      c1[0] = __builtin_amdgcn_mfma_f32_16x16x32_bf16(a1, bmv[0], c1[0], 0, 0, 0);
      c1[1] = __builtin_amdgcn_mfma_f32_16x16x32_bf16(a1, bmv[1], c1[1], 0, 0, 0);
    }
    const int hc0 = wv * 16 + lk * 4;
    const float4 bs = *(const float4*)(b1 + hb * 64 + hc0);
    #pragma unroll
    for (int nt = 0; nt < 2; ++nt) {
      const int tok = nt * 16 + lr;
      const ushort4 pk = make_ushort4(
          f2b(gelu(c1[nt][0] + bs.x)), f2b(gelu(c1[nt][1] + bs.y)),
          f2b(gelu(c1[nt][2] + bs.z)), f2b(gelu(c1[nt][3] + bs.w)));
      *(ushort4*)&Hbuf[tok * HS + hc0] = pk;
    }
  };

  auto stage2 = [&](int hb, const u16* Hbuf) {
    #pragma unroll
    for (int kk2 = 0; kk2 < 2; ++kk2) {
      bf16x8 a2[2];
      #pragma unroll
      for (int mt = 0; mt < 2; ++mt) {
        const u16* pr = &Hbuf[(mt * 16 + lr) * HS + kk2 * 32 + lk * 8];
        const bf16x4 lo = *(const bf16x4*)pr;
        const bf16x4 hi = *(const bf16x4*)(pr + 4);
        a2[mt] = __builtin_shufflevector(lo, hi, 0, 1, 2, 3, 4, 5, 6, 7);
      }
      #pragma unroll
      for (int nf2 = 0; nf2 < 2; ++nf2) {
        const int o16 = wv * 2 + nf2;
        const bf16x8 bw = *(const bf16x8*)(w2f + (((o16 * 8 + hb) * 2 + kk2) * 64 + lane) * 8);
        #pragma unroll
        for (int mt = 0; mt < 2; ++mt)
          oad[mt][nf2] = __builtin_amdgcn_mfma_f32_16x16x32_bf16(a2[mt], bw, oad[mt][nf2], 0, 0, 0);
      }
    }
  };

  u16* H0 = H;
  u16* H1 = H + 32 * HS;
  stage1(0, H0);
  __syncthreads();
  for (int hb = 0; hb < 8; ++hb) {
    u16* cur = (hb & 1) ? H1 : H0;
    u16* nxt = (hb & 1) ? H0 : H1;
    if (hb < 7) stage1(hb + 1, nxt);
    stage2(hb, cur);
    __syncthreads();
  }

  // ---- E: transpose + fc2 bias, then + x1 regs -> out ----
  #pragma unroll
  for (int nf2 = 0; nf2 < 2; ++nf2) {
    const int col = wv * 32 + nf2 * 16 + lr;
    const float bs = fc2b[col];
    #pragma unroll
    for (int mt = 0; mt < 2; ++mt)
      #pragma unroll
      for (int j = 0; j < 4; ++j)
        T32E[(mt * 16 + lk * 4 + j) * 132 + col] = oad[mt][nf2][j] + bs;
  }
  __syncthreads();
  {
    float* orow = outp + (rowbase + rl) * CH;
    #pragma unroll
    for (int i = 0; i < 4; ++i) {
      float4 v = *(const float4*)&T32E[rl * 132 + q * 4 + i * 32];
      v.x += xv[i].x; v.y += xv[i].y; v.z += xv[i].z; v.w += xv[i].w;
      *(float4*)(orow + q * 4 + i * 32) = v;
    }
  }
}

// ---------------------------------------------------------------------------
extern "C" void kernel_launch(void* const* d_in, const int* in_sizes, int n_in,
                              void* d_out, int out_size, void* d_ws, size_t ws_size,
                              hipStream_t stream)
{
  const float* x       = (const float*)d_in[0];
  const float* prompts = (const float*)d_in[1];
  const float* n1g     = (const float*)d_in[2];
  const float* n1b     = (const float*)d_in[3];
  const float* qkv_w   = (const float*)d_in[4];
  const float* qkv_b   = (const float*)d_in[5];
  const float* qkv_la  = (const float*)d_in[6];
  const float* qkv_lb  = (const float*)d_in[7];
  const float* rpb     = (const float*)d_in[8];
  const float* proj_w  = (const float*)d_in[9];
  const float* proj_b  = (const float*)d_in[10];
  const float* proj_la = (const float*)d_in[11];
  const float* proj_lb = (const float*)d_in[12];
  const float* n2g     = (const float*)d_in[13];
  const float* n2b     = (const float*)d_in[14];
  const float* fc1_w   = (const float*)d_in[15];
  const float* fc1_b   = (const float*)d_in[16];
  const float* fc1_la  = (const float*)d_in[17];
  const float* fc1_lb  = (const float*)d_in[18];
  const float* fc2_w   = (const float*)d_in[19];
  const float* fc2_b   = (const float*)d_in[20];
  const float* fc2_la  = (const float*)d_in[21];
  const float* fc2_lb  = (const float*)d_in[22];

  // workspace: [wqf|wprojf|w1f|w2f = 196608 u16] [bm 65536 f32] | tbuf | aobuf
  char* ws = (char*)d_ws;
  u16* wT     = (u16*)ws;
  u16* wqf    = wT;
  u16* wprojf = wT + 49152;
  u16* w1f    = wT + 65536;
  u16* w2f    = wT + 131072;
  float* bm   = (float*)(ws + 393216);
  char* p = ws + 393216 + 262144;
  u16* tbuf  = (u16*)p;                       p += (size_t)MWIN * CH * 2;
  u16* aobuf = (u16*)p;

  fuse_all_kernel<<<768, 256, 0, stream>>>(
      qkv_w, qkv_la, qkv_lb, proj_w, proj_la, proj_lb,
      fc1_w, fc1_la, fc1_lb, fc2_w, fc2_la, fc2_lb, wT);

  bm_kernel<<<256, 256, 0, stream>>>(rpb, bm);

  ln1_gather_kernel<<<MWIN / 4, 256, 0, stream>>>(x, prompts, n1g, n1b, tbuf);

  qkv_attn_kernel<<<BWIN, 256, 0, stream>>>(tbuf, wqf, qkv_b, bm, aobuf);

  proj_mlp_kernel<<<MPIX / 32, 256, 0, stream>>>(
      aobuf, wprojf, proj_b, x, n2g, n2b,
      w1f, fc1_b, w2f, fc2_b, (float*)d_out);
}

// Round 15
// 157.278 us; speedup vs baseline: 1.3897x; 1.0670x over previous
//
#include <hip/hip_runtime.h>

typedef unsigned short u16;
typedef unsigned int   u32;
typedef short bf16x8 __attribute__((ext_vector_type(8)));
typedef short bf16x4 __attribute__((ext_vector_type(4)));
typedef float f32x4  __attribute__((ext_vector_type(4)));

#define HIMG 56
#define WIMG 56
#define CH   128
#define NHEADS 4
#define WSZ  7
#define SSH  3
#define PP   10
#define HIDD 512
#define NWIN 49          // window tokens
#define NTOK 59          // P + NWIN
#define BWIN 2048        // B * NW
#define DH   32          // head dim
#define MPIX 100352      // B * 56 * 56

__device__ __forceinline__ u16 f2b(float f) {
  u32 u = __float_as_uint(f);
  u += 0x7fffu + ((u >> 16) & 1u);
  return (u16)(u >> 16);
}
__device__ __forceinline__ u32 pack2(float a, float b) {
  return (u32)f2b(a) | ((u32)f2b(b) << 16);
}
// fast exact-GELU: Abramowitz-Stegun 7.1.26 erf (max err 1.5e-7) — R7-proven
__device__ __forceinline__ float gelu(float x) {
  const float z = fabsf(x) * 0.70710678118654752f;
  const float t = 1.0f / (1.0f + 0.3275911f * z);
  const float p = t * (0.254829592f + t * (-0.284496736f + t * (1.421413741f +
                  t * (-1.453152027f + t * 1.061405429f))));
  const float erfz = copysignf(1.0f - p * __expf(-z * z), x);
  return 0.5f * x * (1.0f + erfz);
}

// ---------------------------------------------------------------------------
// Fold LoRA into effective weights, MFMA-fragment layouts (R8-proven).
// ---------------------------------------------------------------------------
__global__ void fuse_all_kernel(
    const float* __restrict__ qw,  const float* __restrict__ qa,  const float* __restrict__ qb,
    const float* __restrict__ pw,  const float* __restrict__ pa,  const float* __restrict__ pb,
    const float* __restrict__ f1w, const float* __restrict__ f1a, const float* __restrict__ f1b,
    const float* __restrict__ f2w, const float* __restrict__ f2a, const float* __restrict__ f2b2,
    u16* __restrict__ out)
{
  int idx = blockIdx.x * 256 + threadIdx.x;
  if (idx >= 196608) return;
  int n, k, Nc;
  const float *w, *la, *lb;
  if (idx < 49152) {                    // wqf
    const int li = idx;
    const int j = li & 7, lane = (li >> 3) & 63, kk = (li >> 9) & 3, c16 = li >> 11;
    n = c16 * 16 + (lane & 15);
    k = kk * 32 + (lane >> 4) * 8 + j;
    w = qw; la = qa; lb = qb; Nc = 384;
  } else if (idx < 65536) {             // wprojf
    const int li = idx - 49152;
    const int j = li & 7, lane = (li >> 3) & 63, kk = (li >> 9) & 3, c16 = li >> 11;
    n = c16 * 16 + (lane & 15);
    k = kk * 32 + (lane >> 4) * 8 + j;
    w = pw; la = pa; lb = pb; Nc = 128;
  } else if (idx < 131072) {            // w1f
    const int li = idx - 65536;
    const int j = li & 7, lane = (li >> 3) & 63, kk = (li >> 9) & 3, c16 = li >> 11;
    n = c16 * 16 + (lane & 15);
    k = kk * 32 + (lane >> 4) * 8 + j;
    w = f1w; la = f1a; lb = f1b; Nc = 512;
  } else {                              // w2f
    const int li = idx - 131072;
    const int j = li & 7, lane = (li >> 3) & 63, kk2 = (li >> 9) & 1, hb = (li >> 10) & 7, o16 = li >> 13;
    n = o16 * 16 + (lane & 15);
    k = hb * 64 + kk2 * 32 + (lane >> 4) * 8 + j;
    w = f2w; la = f2a; lb = f2b2; Nc = 128;
  }
  float s = w[k * Nc + n];
  #pragma unroll
  for (int r = 0; r < 4; ++r) s += la[k * 4 + r] * lb[r * Nc + n];
  out[idx] = f2b(s);
}

// ---------------------------------------------------------------------------
// Precompute bias+mask table bm[type][h][64][64] f32.
// ---------------------------------------------------------------------------
__global__ void bm_kernel(const float* __restrict__ rpb, float* __restrict__ bm)
{
  const int idx = blockIdx.x * 256 + threadIdx.x;   // 65536
  const int j = idx & 63, i = (idx >> 6) & 63, h = (idx >> 12) & 3, type = idx >> 14;
  float v = 0.f;
  if (i < 49) {
    if (j >= 59) v = -1e30f;
    else if (j >= PP) {
      const int jw = j - PP;
      const int ih = i / 7, iw = i - ih * 7, jh = jw / 7, jw2 = jw - jh * 7;
      v = rpb[((ih - jh + 6) * 13 + (iw - jw2 + 6)) * NHEADS + h];
      const int wh7 = type >> 1, ww7 = type & 1;
      const int mi = 3 * (wh7 ? (ih < 4 ? 1 : 2) : 0) + (ww7 ? (iw < 4 ? 1 : 2) : 0);
      const int mj = 3 * (wh7 ? (jh < 4 ? 1 : 2) : 0) + (ww7 ? (jw2 < 4 ? 1 : 2) : 0);
      if (mi != mj) v -= 100.f;
    }
  }
  bm[idx] = v;
}

// ---------------------------------------------------------------------------
// FUSED LN1 + qkv GEMM + window attention. One block = one window.
// Phase 0: ln1_gather's proven per-token wave math, writing an XOR-swizzled
//          bf16 t-tile in LDS (overlaid on vt region; consumed before vt use).
// Phases 1-2: R7-R11 proven qkv + attention, af frags read from t_lds.
// ---------------------------------------------------------------------------
#define QKS 136
#define VTS 72
#define PS  68
__global__ __launch_bounds__(256, 3) void qkv_attn_kernel(
    const float* __restrict__ x, const float* __restrict__ prompts,
    const float* __restrict__ n1g, const float* __restrict__ n1b,
    const u16* __restrict__ wqf, const float* __restrict__ qbias,
    const float* __restrict__ bm, u16* __restrict__ attn_out)
{
  __shared__ __align__(16) u16 smem[26624];   // 53248 B -> 3 blocks/CU
  u16* q_lds = smem;                // [64][QKS]
  u16* k_lds = smem + 64 * QKS;     // [64][QKS]
  u16* vt    = smem + 128 * QKS;    // [128][VTS]  (phase 0: t_lds overlay)
  u16* p_lds = smem;                // overlay q+k: [4][64][PS]
  char* t_lds = (char*)vt;          // [64] rows x 256 B, 16B-slot XOR swizzle

  const int tid = threadIdx.x;
  const int wv = tid >> 6, lane = tid & 63;
  const int lr = lane & 15, lk = lane >> 4;
  const int b_ = blockIdx.x;
  const int bimg = b_ >> 6;
  const int wwin = b_ & 63;

  // ---- phase 0: LN1 + roll + window gather -> t_lds ----
  {
    const float2 gg = *(const float2*)(n1g + lane * 2);
    const float2 bv = *(const float2*)(n1b + lane * 2);
    for (int it = 0; it < 16; ++it) {
      const int n = wv * 16 + it;
      if (n >= NTOK) break;                       // uniform per wave
      const float* src;
      if (n < PP) {
        src = prompts + ((size_t)bimg * PP + n) * CH;
      } else {
        const int wi = n - PP;
        const int hr = (wwin >> 3) * WSZ + wi / WSZ;
        const int wc = (wwin & 7) * WSZ + wi % WSZ;
        const int hs = (hr + SSH) % HIMG;
        const int ws2 = (wc + SSH) % WIMG;
        src = x + ((size_t)bimg * (HIMG * WIMG) + hs * WIMG + ws2) * CH;
      }
      const float2 v = *(const float2*)(src + lane * 2);
      u32 pk;
      if (n < PP) {
        pk = pack2(v.x, v.y);
      } else {
        float s = v.x + v.y, s2 = v.x * v.x + v.y * v.y;
        #pragma unroll
        for (int o = 32; o > 0; o >>= 1) { s += __shfl_xor(s, o); s2 += __shfl_xor(s2, o); }
        const float mean = s * (1.0f / CH);
        const float inv  = rsqrtf(s2 * (1.0f / CH) - mean * mean + 1e-5f);
        pk = pack2((v.x - mean) * inv * gg.x + bv.x, (v.y - mean) * inv * gg.y + bv.y);
      }
      const int slot = (lane >> 2) ^ (n & 7);
      *(u32*)(t_lds + n * 256 + slot * 16 + (lane & 3) * 4) = pk;
    }
  }
  __syncthreads();

  // ---- af frags from t_lds (swizzled slots) ----
  bf16x8 af[4][4];
  #pragma unroll
  for (int mt = 0; mt < 4; ++mt) {
    int tok = mt * 16 + lr; if (tok > 58) tok = 58;
    #pragma unroll
    for (int kk = 0; kk < 4; ++kk) {
      const int slot = (kk * 4 + lk) ^ (tok & 7);
      af[mt][kk] = *(const bf16x8*)(t_lds + tok * 256 + slot * 16);
    }
  }
  __syncthreads();   // all t_lds reads done before vt writes overlay it

  // ---- phase 1: qkv ----
  #pragma unroll
  for (int nf = 0; nf < 6; ++nf) {
    const int c = wv * 96 + nf * 16 + lr;
    const int sel = wv * 6 + nf;
    bf16x8 bw[4];
    #pragma unroll
    for (int kk = 0; kk < 4; ++kk)
      bw[kk] = *(const bf16x8*)(wqf + ((sel * 4 + kk) * 64 + lane) * 8);
    f32x4 a4[4];
    #pragma unroll
    for (int mt = 0; mt < 4; ++mt) a4[mt] = (f32x4){0.f, 0.f, 0.f, 0.f};
    #pragma unroll
    for (int kk = 0; kk < 4; ++kk)
      #pragma unroll
      for (int mt = 0; mt < 4; ++mt)
        a4[mt] = __builtin_amdgcn_mfma_f32_16x16x32_bf16(af[mt][kk], bw[kk], a4[mt], 0, 0, 0);
    const float bs = qbias[c];
    #pragma unroll
    for (int mt = 0; mt < 4; ++mt) {
      const int tok0 = mt * 16 + lk * 4;
      if (sel < 8) {
        #pragma unroll
        for (int rg = 0; rg < 4; ++rg)
          q_lds[(tok0 + rg) * QKS + c] = f2b(a4[mt][rg] + bs);
      } else if (sel < 16) {
        #pragma unroll
        for (int rg = 0; rg < 4; ++rg)
          k_lds[(tok0 + rg) * QKS + (c - 128)] = f2b(a4[mt][rg] + bs);
      } else {
        ushort4 pk = make_ushort4(f2b(a4[mt][0] + bs), f2b(a4[mt][1] + bs),
                                  f2b(a4[mt][2] + bs), f2b(a4[mt][3] + bs));
        *(ushort4*)&vt[(c - 256) * VTS + tok0] = pk;
      }
    }
  }
  __syncthreads();

  // ---- phase 2: attention, wave = head h ----
  const int h = wv;
  const int type = (((wwin >> 3) == 7) ? 2 : 0) + (((wwin & 7) == 7) ? 1 : 0);
  const float scale = 0.17677669529663687f;

  bf16x8 kf[4], qf[4];
  #pragma unroll
  for (int t4 = 0; t4 < 4; ++t4) {
    kf[t4] = *(const bf16x8*)&k_lds[(t4 * 16 + lr) * QKS + h * DH + lk * 8];
    int tq = PP + t4 * 16 + lr; if (tq > 63) tq = 63;
    qf[t4] = *(const bf16x8*)&q_lds[tq * QKS + h * DH + lk * 8];
  }
  f32x4 sacc[4][4];
  #pragma unroll
  for (int a = 0; a < 4; ++a)
    #pragma unroll
    for (int b = 0; b < 4; ++b)
      sacc[a][b] = (f32x4){0.f, 0.f, 0.f, 0.f};
  #pragma unroll
  for (int mtj = 0; mtj < 4; ++mtj)
    #pragma unroll
    for (int nti = 0; nti < 4; ++nti)
      sacc[mtj][nti] = __builtin_amdgcn_mfma_f32_16x16x32_bf16(kf[mtj], qf[nti], sacc[mtj][nti], 0, 0, 0);

  const float* bmh = bm + (size_t)(type * NHEADS + h) * 64 * 64;
  #pragma unroll
  for (int nti = 0; nti < 4; ++nti) {
    const int i = nti * 16 + lr;
    float sv[16];
    #pragma unroll
    for (int mtj = 0; mtj < 4; ++mtj) {
      const float4 bmv = *(const float4*)(bmh + i * 64 + mtj * 16 + lk * 4);
      sv[mtj * 4 + 0] = sacc[mtj][nti][0] * scale + bmv.x;
      sv[mtj * 4 + 1] = sacc[mtj][nti][1] * scale + bmv.y;
      sv[mtj * 4 + 2] = sacc[mtj][nti][2] * scale + bmv.z;
      sv[mtj * 4 + 3] = sacc[mtj][nti][3] * scale + bmv.w;
    }
    float mx = sv[0];
    #pragma unroll
    for (int q = 1; q < 16; ++q) mx = fmaxf(mx, sv[q]);
    mx = fmaxf(mx, __shfl_xor(mx, 16));
    mx = fmaxf(mx, __shfl_xor(mx, 32));
    float sum = 0.f;
    #pragma unroll
    for (int q = 0; q < 16; ++q) { sv[q] = __expf(sv[q] - mx); sum += sv[q]; }
    sum += __shfl_xor(sum, 16);
    sum += __shfl_xor(sum, 32);
    const float inv = 1.0f / sum;
    #pragma unroll
    for (int mtj = 0; mtj < 4; ++mtj) {
      sacc[mtj][nti][0] = sv[mtj * 4 + 0] * inv;
      sacc[mtj][nti][1] = sv[mtj * 4 + 1] * inv;
      sacc[mtj][nti][2] = sv[mtj * 4 + 2] * inv;
      sacc[mtj][nti][3] = sv[mtj * 4 + 3] * inv;
    }
  }
  __syncthreads();

  u16* ph = p_lds + h * 64 * PS;
  #pragma unroll
  for (int nti = 0; nti < 4; ++nti) {
    const int i = nti * 16 + lr;
    #pragma unroll
    for (int mtj = 0; mtj < 4; ++mtj) {
      const ushort4 pk = make_ushort4(f2b(sacc[mtj][nti][0]), f2b(sacc[mtj][nti][1]),
                                      f2b(sacc[mtj][nti][2]), f2b(sacc[mtj][nti][3]));
      *(ushort4*)&ph[i * PS + mtj * 16 + lk * 4] = pk;
    }
  }
  __syncthreads();

  f32x4 oacc[4][2];
  #pragma unroll
  for (int a = 0; a < 4; ++a) { oacc[a][0] = (f32x4){0,0,0,0}; oacc[a][1] = (f32x4){0,0,0,0}; }
  #pragma unroll
  for (int ks = 0; ks < 2; ++ks) {
    bf16x8 pa[4];
    #pragma unroll
    for (int mt = 0; mt < 4; ++mt) {
      const u16* pr = &ph[(mt * 16 + lr) * PS + ks * 32 + lk * 8];
      const bf16x4 lo = *(const bf16x4*)pr;
      const bf16x4 hi = *(const bf16x4*)(pr + 4);
      pa[mt] = __builtin_shufflevector(lo, hi, 0, 1, 2, 3, 4, 5, 6, 7);
    }
    bf16x8 bv[2];
    #pragma unroll
    for (int nd = 0; nd < 2; ++nd)
      bv[nd] = *(const bf16x8*)&vt[(h * DH + nd * 16 + lr) * VTS + ks * 32 + lk * 8];
    #pragma unroll
    for (int mt = 0; mt < 4; ++mt)
      #pragma unroll
      for (int nd = 0; nd < 2; ++nd)
        oacc[mt][nd] = __builtin_amdgcn_mfma_f32_16x16x32_bf16(pa[mt], bv[nd], oacc[mt][nd], 0, 0, 0);
  }

  #pragma unroll
  for (int mt = 0; mt < 4; ++mt)
    #pragma unroll
    for (int rg = 0; rg < 4; ++rg) {
      const int i = mt * 16 + lk * 4 + rg;
      ph[i * PS + lr]      = f2b(oacc[mt][0][rg]);
      ph[i * PS + 16 + lr] = f2b(oacc[mt][1][rg]);
    }
  __syncthreads();
  if (lane < NWIN) {
    const u16* src = &ph[lane * PS];
    u16* dst = attn_out + ((size_t)b_ * NWIN + lane) * CH + h * DH;
    #pragma unroll
    for (int c = 0; c < 8; ++c)
      *(uint2*)(dst + c * 4) = *(const uint2*)(src + c * 4);
  }
}

// ---------------------------------------------------------------------------
// FUSED proj + LN2 + MLP (R11-proven exact: 33792B LDS, 4 blocks/CU, ~90 us).
// ---------------------------------------------------------------------------
#define HS 68
__global__ __launch_bounds__(256, 4) void proj_mlp_kernel(
    const u16* __restrict__ ao, const u16* __restrict__ wprojf,
    const float* __restrict__ pbias, const float* __restrict__ x,
    const float* __restrict__ g2, const float* __restrict__ b2,
    const u16* __restrict__ w1f, const float* __restrict__ b1,
    const u16* __restrict__ w2f, const float* __restrict__ fc2b,
    float* __restrict__ outp)
{
  __shared__ __align__(16) char smem[33792];
  u16*   sa  = (u16*)smem;              // [32][128] gathered ao tile
  float* T32 = (float*)smem;            // [32][132] transpose buffer
  u16*   sm  = (u16*)(smem + 16896);    // [32][128] m tile, swizzle16
  u16*   H   = (u16*)(smem + 25088);    // [2][32][HS]
  const int tid = threadIdx.x;
  const int wv = tid >> 6, lane = tid & 63;
  const int lr = lane & 15, lk = lane >> 4;
  const long rowbase = (long)blockIdx.x * 32;

  // ---- A: gather ao rows (inverse window map), swizzle16 source ----
  #pragma unroll
  for (int it = 0; it < 2; ++it) {
    const int c = it * 256 + tid;
    const int r = c >> 4, s = c & 15;
    const int k8 = s ^ (r & 15);
    const int pix = (int)rowbase + r;
    const int b  = pix / 3136;
    const int rem = pix - b * 3136;
    const int hf = rem / 56, wf = rem - hf * 56;
    int hs = hf + 53; if (hs >= 56) hs -= 56;
    int ws2 = wf + 53; if (ws2 >= 56) ws2 -= 56;
    const int w  = (hs / 7) * 8 + (ws2 / 7);
    const int wi = (hs % 7) * 7 + (ws2 % 7);
    const long arow = ((long)b * 64 + w) * NWIN + wi;
    __builtin_amdgcn_global_load_lds((const void*)(ao + arow * CH + k8 * 8),
                                     (void*)(sa + c * 8), 16, 0, 0);
  }
  __syncthreads();

  // ---- B: proj MFMA ----
  f32x4 pacc[2][2];
  #pragma unroll
  for (int a = 0; a < 2; ++a) { pacc[a][0] = (f32x4){0,0,0,0}; pacc[a][1] = (f32x4){0,0,0,0}; }
  #pragma unroll
  for (int kk = 0; kk < 4; ++kk) {
    bf16x8 af[2];
    #pragma unroll
    for (int mt = 0; mt < 2; ++mt) {
      const int r = mt * 16 + lr;
      af[mt] = *(const bf16x8*)(sa + r * 128 + (((kk * 4 + lk) ^ (r & 15)) << 3));
    }
    #pragma unroll
    for (int nf = 0; nf < 2; ++nf) {
      const int c16 = wv * 2 + nf;
      const bf16x8 bw = *(const bf16x8*)(wprojf + ((c16 * 4 + kk) * 64 + lane) * 8);
      #pragma unroll
      for (int mt = 0; mt < 2; ++mt)
        pacc[mt][nf] = __builtin_amdgcn_mfma_f32_16x16x32_bf16(af[mt], bw, pacc[mt][nf], 0, 0, 0);
    }
  }
  __syncthreads();   // sa reads complete before T32 overlays it

  // ---- C: transpose + x residual + LN2 -> x1 regs + sm ----
  #pragma unroll
  for (int nf = 0; nf < 2; ++nf) {
    const int col = (wv * 2 + nf) * 16 + lr;
    const float bs = pbias[col];
    #pragma unroll
    for (int mt = 0; mt < 2; ++mt)
      #pragma unroll
      for (int j = 0; j < 4; ++j)
        T32[(mt * 16 + lk * 4 + j) * 132 + col] = pacc[mt][nf][j] + bs;
  }
  __syncthreads();
  const int rl = tid >> 3, q = tid & 7;      // 32 rows x 8 threads/row
  float4 xv[4];
  float sum = 0.f, sq = 0.f;
  {
    const float* xrow = x + (rowbase + rl) * CH;
    #pragma unroll
    for (int i = 0; i < 4; ++i) {
      float4 tv = *(const float4*)&T32[rl * 132 + q * 4 + i * 32];
      const float4 xr = *(const float4*)(xrow + q * 4 + i * 32);
      tv.x += xr.x; tv.y += xr.y; tv.z += xr.z; tv.w += xr.w;
      xv[i] = tv;
      sum += tv.x + tv.y + tv.z + tv.w;
      sq  += tv.x * tv.x + tv.y * tv.y + tv.z * tv.z + tv.w * tv.w;
    }
  }
  sum += __shfl_xor(sum, 1); sq += __shfl_xor(sq, 1);
  sum += __shfl_xor(sum, 2); sq += __shfl_xor(sq, 2);
  sum += __shfl_xor(sum, 4); sq += __shfl_xor(sq, 4);
  {
    const float mean = sum * (1.0f / CH);
    const float inv  = rsqrtf(sq * (1.0f / CH) - mean * mean + 1e-5f);
    #pragma unroll
    for (int i = 0; i < 4; ++i) {
      const int col0 = q * 4 + i * 32;
      const float4 gg = *(const float4*)(g2 + col0);
      const float4 bb = *(const float4*)(b2 + col0);
      const float m0 = (xv[i].x - mean) * inv * gg.x + bb.x;
      const float m1 = (xv[i].y - mean) * inv * gg.y + bb.y;
      const float m2 = (xv[i].z - mean) * inv * gg.z + bb.z;
      const float m3 = (xv[i].w - mean) * inv * gg.w + bb.w;
      const int slot = col0 >> 3;
      const int off = rl * 128 + ((slot ^ (rl & 15)) << 3) + (col0 & 7);
      uint2 pk; pk.x = pack2(m0, m1); pk.y = pack2(m2, m3);
      *(uint2*)&sm[off] = pk;
    }
  }
  __syncthreads();

  // ---- D: MLP (R10-proven), reading sm ----
  f32x4 oad[2][2];
  #pragma unroll
  for (int a = 0; a < 2; ++a) { oad[a][0] = (f32x4){0,0,0,0}; oad[a][1] = (f32x4){0,0,0,0}; }

  auto stage1 = [&](int hb, u16* Hbuf) {
    f32x4 c1[2];
    c1[0] = (f32x4){0.f, 0.f, 0.f, 0.f};
    c1[1] = (f32x4){0.f, 0.f, 0.f, 0.f};
    #pragma unroll
    for (int kk = 0; kk < 4; ++kk) {
      const int c16 = hb * 4 + wv;
      const bf16x8 a1 = *(const bf16x8*)(w1f + ((c16 * 4 + kk) * 64 + lane) * 8);
      bf16x8 bmv[2];
      #pragma unroll
      for (int nt = 0; nt < 2; ++nt) {
        const int r = nt * 16 + lr;
        bmv[nt] = *(const bf16x8*)(sm + r * 128 + (((kk * 4 + lk) ^ (r & 15)) << 3));
      }
      c1[0] = __builtin_amdgcn_mfma_f32_16x16x32_bf16(a1, bmv[0], c1[0], 0, 0, 0);
      c1[1] = __builtin_amdgcn_mfma_f32_16x16x32_bf16(a1, bmv[1], c1[1], 0, 0, 0);
    }
    const int hc0 = wv * 16 + lk * 4;
    const float4 bs = *(const float4*)(b1 + hb * 64 + hc0);
    #pragma unroll
    for (int nt = 0; nt < 2; ++nt) {
      const int tok = nt * 16 + lr;
      const ushort4 pk = make_ushort4(
          f2b(gelu(c1[nt][0] + bs.x)), f2b(gelu(c1[nt][1] + bs.y)),
          f2b(gelu(c1[nt][2] + bs.z)), f2b(gelu(c1[nt][3] + bs.w)));
      *(ushort4*)&Hbuf[tok * HS + hc0] = pk;
    }
  };

  auto stage2 = [&](int hb, const u16* Hbuf) {
    #pragma unroll
    for (int kk2 = 0; kk2 < 2; ++kk2) {
      bf16x8 a2[2];
      #pragma unroll
      for (int mt = 0; mt < 2; ++mt) {
        const u16* pr = &Hbuf[(mt * 16 + lr) * HS + kk2 * 32 + lk * 8];
        const bf16x4 lo = *(const bf16x4*)pr;
        const bf16x4 hi = *(const bf16x4*)(pr + 4);
        a2[mt] = __builtin_shufflevector(lo, hi, 0, 1, 2, 3, 4, 5, 6, 7);
      }
      #pragma unroll
      for (int nf2 = 0; nf2 < 2; ++nf2) {
        const int o16 = wv * 2 + nf2;
        const bf16x8 bw = *(const bf16x8*)(w2f + (((o16 * 8 + hb) * 2 + kk2) * 64 + lane) * 8);
        #pragma unroll
        for (int mt = 0; mt < 2; ++mt)
          oad[mt][nf2] = __builtin_amdgcn_mfma_f32_16x16x32_bf16(a2[mt], bw, oad[mt][nf2], 0, 0, 0);
      }
    }
  };

  u16* H0 = H;
  u16* H1 = H + 32 * HS;
  stage1(0, H0);
  __syncthreads();
  for (int hb = 0; hb < 8; ++hb) {
    u16* cur = (hb & 1) ? H1 : H0;
    u16* nxt = (hb & 1) ? H0 : H1;
    if (hb < 7) stage1(hb + 1, nxt);
    stage2(hb, cur);
    __syncthreads();
  }

  // ---- E: transpose + fc2 bias, then + x1 regs -> out ----
  #pragma unroll
  for (int nf2 = 0; nf2 < 2; ++nf2) {
    const int col = wv * 32 + nf2 * 16 + lr;
    const float bs = fc2b[col];
    #pragma unroll
    for (int mt = 0; mt < 2; ++mt)
      #pragma unroll
      for (int j = 0; j < 4; ++j)
        T32[(mt * 16 + lk * 4 + j) * 132 + col] = oad[mt][nf2][j] + bs;
  }
  __syncthreads();
  {
    float* orow = outp + (rowbase + rl) * CH;
    #pragma unroll
    for (int i = 0; i < 4; ++i) {
      float4 v = *(const float4*)&T32[rl * 132 + q * 4 + i * 32];
      v.x += xv[i].x; v.y += xv[i].y; v.z += xv[i].z; v.w += xv[i].w;
      *(float4*)(orow + q * 4 + i * 32) = v;
    }
  }
}

// ---------------------------------------------------------------------------
extern "C" void kernel_launch(void* const* d_in, const int* in_sizes, int n_in,
                              void* d_out, int out_size, void* d_ws, size_t ws_size,
                              hipStream_t stream)
{
  const float* x       = (const float*)d_in[0];
  const float* prompts = (const float*)d_in[1];
  const float* n1g     = (const float*)d_in[2];
  const float* n1b     = (const float*)d_in[3];
  const float* qkv_w   = (const float*)d_in[4];
  const float* qkv_b   = (const float*)d_in[5];
  const float* qkv_la  = (const float*)d_in[6];
  const float* qkv_lb  = (const float*)d_in[7];
  const float* rpb     = (const float*)d_in[8];
  const float* proj_w  = (const float*)d_in[9];
  const float* proj_b  = (const float*)d_in[10];
  const float* proj_la = (const float*)d_in[11];
  const float* proj_lb = (const float*)d_in[12];
  const float* n2g     = (const float*)d_in[13];
  const float* n2b     = (const float*)d_in[14];
  const float* fc1_w   = (const float*)d_in[15];
  const float* fc1_b   = (const float*)d_in[16];
  const float* fc1_la  = (const float*)d_in[17];
  const float* fc1_lb  = (const float*)d_in[18];
  const float* fc2_w   = (const float*)d_in[19];
  const float* fc2_b   = (const float*)d_in[20];
  const float* fc2_la  = (const float*)d_in[21];
  const float* fc2_lb  = (const float*)d_in[22];

  // workspace: [wqf|wprojf|w1f|w2f = 196608 u16] [bm 65536 f32] | aobuf
  char* ws = (char*)d_ws;
  u16* wT     = (u16*)ws;
  u16* wqf    = wT;
  u16* wprojf = wT + 49152;
  u16* w1f    = wT + 65536;
  u16* w2f    = wT + 131072;
  float* bm   = (float*)(ws + 393216);
  u16* aobuf  = (u16*)(ws + 393216 + 262144);

  fuse_all_kernel<<<768, 256, 0, stream>>>(
      qkv_w, qkv_la, qkv_lb, proj_w, proj_la, proj_lb,
      fc1_w, fc1_la, fc1_lb, fc2_w, fc2_la, fc2_lb, wT);

  bm_kernel<<<256, 256, 0, stream>>>(rpb, bm);

  qkv_attn_kernel<<<BWIN, 256, 0, stream>>>(
      x, prompts, n1g, n1b, wqf, qkv_b, bm, aobuf);

  proj_mlp_kernel<<<MPIX / 32, 256, 0, stream>>>(
      aobuf, wprojf, proj_b, x, n2g, n2b,
      w1f, fc1_b, w2f, fc2_b, (float*)d_out);
}

// Round 16
// 154.627 us; speedup vs baseline: 1.4135x; 1.0171x over previous
//
#include <hip/hip_runtime.h>
#include <hip/hip_bf16.h>

typedef unsigned short u16;
typedef unsigned int   u32;
typedef short bf16x8 __attribute__((ext_vector_type(8)));
typedef short bf16x4 __attribute__((ext_vector_type(4)));
typedef float f32x4  __attribute__((ext_vector_type(4)));

#define HIMG 56
#define WIMG 56
#define CH   128
#define NHEADS 4
#define WSZ  7
#define SSH  3
#define PP   10
#define HIDD 512
#define NWIN 49          // window tokens
#define NTOK 59          // P + NWIN
#define BWIN 2048        // B * NW
#define DH   32          // head dim
#define MPIX 100352      // B * 56 * 56

// pack two f32 -> two bf16 (RTNE) via v_cvt_pk_bf16_f32 (1 VALU op)
__device__ __forceinline__ u32 pack2(float a, float b) {
  union { __hip_bfloat162 h; u32 u; } cv;
  cv.h = __float22bfloat162_rn(make_float2(a, b));
  return cv.u;
}
__device__ __forceinline__ u16 f2b(float f) {
  u32 u = __float_as_uint(f);
  u += 0x7fffu + ((u >> 16) & 1u);
  return (u16)(u >> 16);
}
// fast exact-GELU: Abramowitz-Stegun 7.1.26 erf (max err 1.5e-7) — R7-proven
__device__ __forceinline__ float gelu(float x) {
  const float z = fabsf(x) * 0.70710678118654752f;
  const float t = 1.0f / (1.0f + 0.3275911f * z);
  const float p = t * (0.254829592f + t * (-0.284496736f + t * (1.421413741f +
                  t * (-1.453152027f + t * 1.061405429f))));
  const float erfz = copysignf(1.0f - p * __expf(-z * z), x);
  return 0.5f * x * (1.0f + erfz);
}

// ---------------------------------------------------------------------------
// Fold LoRA into effective weights, MFMA-fragment layouts (R8-proven).
// ---------------------------------------------------------------------------
__global__ void fuse_all_kernel(
    const float* __restrict__ qw,  const float* __restrict__ qa,  const float* __restrict__ qb,
    const float* __restrict__ pw,  const float* __restrict__ pa,  const float* __restrict__ pb,
    const float* __restrict__ f1w, const float* __restrict__ f1a, const float* __restrict__ f1b,
    const float* __restrict__ f2w, const float* __restrict__ f2a, const float* __restrict__ f2b2,
    u16* __restrict__ out)
{
  int idx = blockIdx.x * 256 + threadIdx.x;
  if (idx >= 196608) return;
  int n, k, Nc;
  const float *w, *la, *lb;
  if (idx < 49152) {                    // wqf
    const int li = idx;
    const int j = li & 7, lane = (li >> 3) & 63, kk = (li >> 9) & 3, c16 = li >> 11;
    n = c16 * 16 + (lane & 15);
    k = kk * 32 + (lane >> 4) * 8 + j;
    w = qw; la = qa; lb = qb; Nc = 384;
  } else if (idx < 65536) {             // wprojf
    const int li = idx - 49152;
    const int j = li & 7, lane = (li >> 3) & 63, kk = (li >> 9) & 3, c16 = li >> 11;
    n = c16 * 16 + (lane & 15);
    k = kk * 32 + (lane >> 4) * 8 + j;
    w = pw; la = pa; lb = pb; Nc = 128;
  } else if (idx < 131072) {            // w1f
    const int li = idx - 65536;
    const int j = li & 7, lane = (li >> 3) & 63, kk = (li >> 9) & 3, c16 = li >> 11;
    n = c16 * 16 + (lane & 15);
    k = kk * 32 + (lane >> 4) * 8 + j;
    w = f1w; la = f1a; lb = f1b; Nc = 512;
  } else {                              // w2f
    const int li = idx - 131072;
    const int j = li & 7, lane = (li >> 3) & 63, kk2 = (li >> 9) & 1, hb = (li >> 10) & 7, o16 = li >> 13;
    n = o16 * 16 + (lane & 15);
    k = hb * 64 + kk2 * 32 + (lane >> 4) * 8 + j;
    w = f2w; la = f2a; lb = f2b2; Nc = 128;
  }
  float s = w[k * Nc + n];
  #pragma unroll
  for (int r = 0; r < 4; ++r) s += la[k * 4 + r] * lb[r * Nc + n];
  out[idx] = f2b(s);
}

// ---------------------------------------------------------------------------
// Precompute bias+mask table bm[type][h][64][64] f32.
// ---------------------------------------------------------------------------
__global__ void bm_kernel(const float* __restrict__ rpb, float* __restrict__ bm)
{
  const int idx = blockIdx.x * 256 + threadIdx.x;   // 65536
  const int j = idx & 63, i = (idx >> 6) & 63, h = (idx >> 12) & 3, type = idx >> 14;
  float v = 0.f;
  if (i < 49) {
    if (j >= 59) v = -1e30f;
    else if (j >= PP) {
      const int jw = j - PP;
      const int ih = i / 7, iw = i - ih * 7, jh = jw / 7, jw2 = jw - jh * 7;
      v = rpb[((ih - jh + 6) * 13 + (iw - jw2 + 6)) * NHEADS + h];
      const int wh7 = type >> 1, ww7 = type & 1;
      const int mi = 3 * (wh7 ? (ih < 4 ? 1 : 2) : 0) + (ww7 ? (iw < 4 ? 1 : 2) : 0);
      const int mj = 3 * (wh7 ? (jh < 4 ? 1 : 2) : 0) + (ww7 ? (jw2 < 4 ? 1 : 2) : 0);
      if (mi != mj) v -= 100.f;
    }
  }
  bm[idx] = v;
}

// ---------------------------------------------------------------------------
// FUSED LN1 + qkv GEMM + window attention (R15-proven structure).
// ---------------------------------------------------------------------------
#define QKS 136
#define VTS 72
#define PS  68
__global__ __launch_bounds__(256, 3) void qkv_attn_kernel(
    const float* __restrict__ x, const float* __restrict__ prompts,
    const float* __restrict__ n1g, const float* __restrict__ n1b,
    const u16* __restrict__ wqf, const float* __restrict__ qbias,
    const float* __restrict__ bm, u16* __restrict__ attn_out)
{
  __shared__ __align__(16) u16 smem[26624];   // 53248 B -> 3 blocks/CU
  u16* q_lds = smem;                // [64][QKS]
  u16* k_lds = smem + 64 * QKS;     // [64][QKS]
  u16* vt    = smem + 128 * QKS;    // [128][VTS]  (phase 0: t_lds overlay)
  u16* p_lds = smem;                // overlay q+k: [4][64][PS]
  char* t_lds = (char*)vt;          // [64] rows x 256 B, 16B-slot XOR swizzle

  const int tid = threadIdx.x;
  const int wv = tid >> 6, lane = tid & 63;
  const int lr = lane & 15, lk = lane >> 4;
  const int b_ = blockIdx.x;
  const int bimg = b_ >> 6;
  const int wwin = b_ & 63;

  // ---- phase 0: LN1 + roll + window gather -> t_lds ----
  {
    const float2 gg = *(const float2*)(n1g + lane * 2);
    const float2 bv = *(const float2*)(n1b + lane * 2);
    for (int it = 0; it < 16; ++it) {
      const int n = wv * 16 + it;
      if (n >= NTOK) break;                       // uniform per wave
      const float* src;
      if (n < PP) {
        src = prompts + ((size_t)bimg * PP + n) * CH;
      } else {
        const int wi = n - PP;
        const int hr = (wwin >> 3) * WSZ + wi / WSZ;
        const int wc = (wwin & 7) * WSZ + wi % WSZ;
        const int hs = (hr + SSH) % HIMG;
        const int ws2 = (wc + SSH) % WIMG;
        src = x + ((size_t)bimg * (HIMG * WIMG) + hs * WIMG + ws2) * CH;
      }
      const float2 v = *(const float2*)(src + lane * 2);
      u32 pk;
      if (n < PP) {
        pk = pack2(v.x, v.y);
      } else {
        float s = v.x + v.y, s2 = v.x * v.x + v.y * v.y;
        #pragma unroll
        for (int o = 32; o > 0; o >>= 1) { s += __shfl_xor(s, o); s2 += __shfl_xor(s2, o); }
        const float mean = s * (1.0f / CH);
        const float inv  = rsqrtf(s2 * (1.0f / CH) - mean * mean + 1e-5f);
        pk = pack2((v.x - mean) * inv * gg.x + bv.x, (v.y - mean) * inv * gg.y + bv.y);
      }
      const int slot = (lane >> 2) ^ (n & 7);
      *(u32*)(t_lds + n * 256 + slot * 16 + (lane & 3) * 4) = pk;
    }
  }
  __syncthreads();

  // ---- af frags from t_lds (swizzled slots) ----
  bf16x8 af[4][4];
  #pragma unroll
  for (int mt = 0; mt < 4; ++mt) {
    int tok = mt * 16 + lr; if (tok > 58) tok = 58;
    #pragma unroll
    for (int kk = 0; kk < 4; ++kk) {
      const int slot = (kk * 4 + lk) ^ (tok & 7);
      af[mt][kk] = *(const bf16x8*)(t_lds + tok * 256 + slot * 16);
    }
  }
  __syncthreads();   // all t_lds reads done before vt writes overlay it

  // ---- phase 1: qkv ----
  #pragma unroll
  for (int nf = 0; nf < 6; ++nf) {
    const int c = wv * 96 + nf * 16 + lr;
    const int sel = wv * 6 + nf;
    bf16x8 bw[4];
    #pragma unroll
    for (int kk = 0; kk < 4; ++kk)
      bw[kk] = *(const bf16x8*)(wqf + ((sel * 4 + kk) * 64 + lane) * 8);
    f32x4 a4[4];
    #pragma unroll
    for (int mt = 0; mt < 4; ++mt) a4[mt] = (f32x4){0.f, 0.f, 0.f, 0.f};
    #pragma unroll
    for (int kk = 0; kk < 4; ++kk)
      #pragma unroll
      for (int mt = 0; mt < 4; ++mt)
        a4[mt] = __builtin_amdgcn_mfma_f32_16x16x32_bf16(af[mt][kk], bw[kk], a4[mt], 0, 0, 0);
    const float bs = qbias[c];
    #pragma unroll
    for (int mt = 0; mt < 4; ++mt) {
      const int tok0 = mt * 16 + lk * 4;
      if (sel < 8) {
        #pragma unroll
        for (int rg = 0; rg < 4; rg += 2) {
          const u32 pk = pack2(a4[mt][rg] + bs, a4[mt][rg + 1] + bs);
          q_lds[(tok0 + rg) * QKS + c]     = (u16)pk;
          q_lds[(tok0 + rg + 1) * QKS + c] = (u16)(pk >> 16);
        }
      } else if (sel < 16) {
        #pragma unroll
        for (int rg = 0; rg < 4; rg += 2) {
          const u32 pk = pack2(a4[mt][rg] + bs, a4[mt][rg + 1] + bs);
          k_lds[(tok0 + rg) * QKS + (c - 128)]     = (u16)pk;
          k_lds[(tok0 + rg + 1) * QKS + (c - 128)] = (u16)(pk >> 16);
        }
      } else {
        uint2 pk2;
        pk2.x = pack2(a4[mt][0] + bs, a4[mt][1] + bs);
        pk2.y = pack2(a4[mt][2] + bs, a4[mt][3] + bs);
        *(uint2*)&vt[(c - 256) * VTS + tok0] = pk2;
      }
    }
  }
  __syncthreads();

  // ---- phase 2: attention, wave = head h ----
  const int h = wv;
  const int type = (((wwin >> 3) == 7) ? 2 : 0) + (((wwin & 7) == 7) ? 1 : 0);
  const float scale = 0.17677669529663687f;

  bf16x8 kf[4], qf[4];
  #pragma unroll
  for (int t4 = 0; t4 < 4; ++t4) {
    kf[t4] = *(const bf16x8*)&k_lds[(t4 * 16 + lr) * QKS + h * DH + lk * 8];
    int tq = PP + t4 * 16 + lr; if (tq > 63) tq = 63;
    qf[t4] = *(const bf16x8*)&q_lds[tq * QKS + h * DH + lk * 8];
  }
  f32x4 sacc[4][4];
  #pragma unroll
  for (int a = 0; a < 4; ++a)
    #pragma unroll
    for (int b = 0; b < 4; ++b)
      sacc[a][b] = (f32x4){0.f, 0.f, 0.f, 0.f};
  #pragma unroll
  for (int mtj = 0; mtj < 4; ++mtj)
    #pragma unroll
    for (int nti = 0; nti < 4; ++nti)
      sacc[mtj][nti] = __builtin_amdgcn_mfma_f32_16x16x32_bf16(kf[mtj], qf[nti], sacc[mtj][nti], 0, 0, 0);

  const float* bmh = bm + (size_t)(type * NHEADS + h) * 64 * 64;
  #pragma unroll
  for (int nti = 0; nti < 4; ++nti) {
    const int i = nti * 16 + lr;
    float sv[16];
    #pragma unroll
    for (int mtj = 0; mtj < 4; ++mtj) {
      const float4 bmv = *(const float4*)(bmh + i * 64 + mtj * 16 + lk * 4);
      sv[mtj * 4 + 0] = sacc[mtj][nti][0] * scale + bmv.x;
      sv[mtj * 4 + 1] = sacc[mtj][nti][1] * scale + bmv.y;
      sv[mtj * 4 + 2] = sacc[mtj][nti][2] * scale + bmv.z;
      sv[mtj * 4 + 3] = sacc[mtj][nti][3] * scale + bmv.w;
    }
    float mx = sv[0];
    #pragma unroll
    for (int q = 1; q < 16; ++q) mx = fmaxf(mx, sv[q]);
    mx = fmaxf(mx, __shfl_xor(mx, 16));
    mx = fmaxf(mx, __shfl_xor(mx, 32));
    float sum = 0.f;
    #pragma unroll
    for (int q = 0; q < 16; ++q) { sv[q] = __expf(sv[q] - mx); sum += sv[q]; }
    sum += __shfl_xor(sum, 16);
    sum += __shfl_xor(sum, 32);
    const float inv = 1.0f / sum;
    #pragma unroll
    for (int mtj = 0; mtj < 4; ++mtj) {
      sacc[mtj][nti][0] = sv[mtj * 4 + 0] * inv;
      sacc[mtj][nti][1] = sv[mtj * 4 + 1] * inv;
      sacc[mtj][nti][2] = sv[mtj * 4 + 2] * inv;
      sacc[mtj][nti][3] = sv[mtj * 4 + 3] * inv;
    }
  }
  __syncthreads();

  u16* ph = p_lds + h * 64 * PS;
  #pragma unroll
  for (int nti = 0; nti < 4; ++nti) {
    const int i = nti * 16 + lr;
    #pragma unroll
    for (int mtj = 0; mtj < 4; ++mtj) {
      uint2 pk2;
      pk2.x = pack2(sacc[mtj][nti][0], sacc[mtj][nti][1]);
      pk2.y = pack2(sacc[mtj][nti][2], sacc[mtj][nti][3]);
      *(uint2*)&ph[i * PS + mtj * 16 + lk * 4] = pk2;
    }
  }
  __syncthreads();

  f32x4 oacc[4][2];
  #pragma unroll
  for (int a = 0; a < 4; ++a) { oacc[a][0] = (f32x4){0,0,0,0}; oacc[a][1] = (f32x4){0,0,0,0}; }
  #pragma unroll
  for (int ks = 0; ks < 2; ++ks) {
    bf16x8 pa[4];
    #pragma unroll
    for (int mt = 0; mt < 4; ++mt) {
      const u16* pr = &ph[(mt * 16 + lr) * PS + ks * 32 + lk * 8];
      const bf16x4 lo = *(const bf16x4*)pr;
      const bf16x4 hi = *(const bf16x4*)(pr + 4);
      pa[mt] = __builtin_shufflevector(lo, hi, 0, 1, 2, 3, 4, 5, 6, 7);
    }
    bf16x8 bv[2];
    #pragma unroll
    for (int nd = 0; nd < 2; ++nd)
      bv[nd] = *(const bf16x8*)&vt[(h * DH + nd * 16 + lr) * VTS + ks * 32 + lk * 8];
    #pragma unroll
    for (int mt = 0; mt < 4; ++mt)
      #pragma unroll
      for (int nd = 0; nd < 2; ++nd)
        oacc[mt][nd] = __builtin_amdgcn_mfma_f32_16x16x32_bf16(pa[mt], bv[nd], oacc[mt][nd], 0, 0, 0);
  }

  #pragma unroll
  for (int mt = 0; mt < 4; ++mt)
    #pragma unroll
    for (int rg = 0; rg < 4; ++rg) {
      const int i = mt * 16 + lk * 4 + rg;
      const u32 pk = pack2(oacc[mt][0][rg], oacc[mt][1][rg]);
      ph[i * PS + lr]      = (u16)pk;
      ph[i * PS + 16 + lr] = (u16)(pk >> 16);
    }
  __syncthreads();
  if (lane < NWIN) {
    const u16* src = &ph[lane * PS];
    u16* dst = attn_out + ((size_t)b_ * NWIN + lane) * CH + h * DH;
    #pragma unroll
    for (int c = 0; c < 8; ++c)
      *(uint2*)(dst + c * 4) = *(const uint2*)(src + c * 4);
  }
}

// ---------------------------------------------------------------------------
// FUSED proj + LN2 + MLP (R11/R15-proven: 33792B LDS, 4 blocks/CU).
// ---------------------------------------------------------------------------
#define HS 68
__global__ __launch_bounds__(256, 4) void proj_mlp_kernel(
    const u16* __restrict__ ao, const u16* __restrict__ wprojf,
    const float* __restrict__ pbias, const float* __restrict__ x,
    const float* __restrict__ g2, const float* __restrict__ b2,
    const u16* __restrict__ w1f, const float* __restrict__ b1,
    const u16* __restrict__ w2f, const float* __restrict__ fc2b,
    float* __restrict__ outp)
{
  __shared__ __align__(16) char smem[33792];
  u16*   sa  = (u16*)smem;              // [32][128] gathered ao tile
  float* T32 = (float*)smem;            // [32][132] transpose buffer
  u16*   sm  = (u16*)(smem + 16896);    // [32][128] m tile, swizzle16
  u16*   H   = (u16*)(smem + 25088);    // [2][32][HS]
  const int tid = threadIdx.x;
  const int wv = tid >> 6, lane = tid & 63;
  const int lr = lane & 15, lk = lane >> 4;
  const long rowbase = (long)blockIdx.x * 32;

  // ---- A: gather ao rows (inverse window map), swizzle16 source ----
  #pragma unroll
  for (int it = 0; it < 2; ++it) {
    const int c = it * 256 + tid;
    const int r = c >> 4, s = c & 15;
    const int k8 = s ^ (r & 15);
    const int pix = (int)rowbase + r;
    const int b  = pix / 3136;
    const int rem = pix - b * 3136;
    const int hf = rem / 56, wf = rem - hf * 56;
    int hs = hf + 53; if (hs >= 56) hs -= 56;
    int ws2 = wf + 53; if (ws2 >= 56) ws2 -= 56;
    const int w  = (hs / 7) * 8 + (ws2 / 7);
    const int wi = (hs % 7) * 7 + (ws2 % 7);
    const long arow = ((long)b * 64 + w) * NWIN + wi;
    __builtin_amdgcn_global_load_lds((const void*)(ao + arow * CH + k8 * 8),
                                     (void*)(sa + c * 8), 16, 0, 0);
  }
  __syncthreads();

  // ---- B: proj MFMA ----
  f32x4 pacc[2][2];
  #pragma unroll
  for (int a = 0; a < 2; ++a) { pacc[a][0] = (f32x4){0,0,0,0}; pacc[a][1] = (f32x4){0,0,0,0}; }
  #pragma unroll
  for (int kk = 0; kk < 4; ++kk) {
    bf16x8 af[2];
    #pragma unroll
    for (int mt = 0; mt < 2; ++mt) {
      const int r = mt * 16 + lr;
      af[mt] = *(const bf16x8*)(sa + r * 128 + (((kk * 4 + lk) ^ (r & 15)) << 3));
    }
    #pragma unroll
    for (int nf = 0; nf < 2; ++nf) {
      const int c16 = wv * 2 + nf;
      const bf16x8 bw = *(const bf16x8*)(wprojf + ((c16 * 4 + kk) * 64 + lane) * 8);
      #pragma unroll
      for (int mt = 0; mt < 2; ++mt)
        pacc[mt][nf] = __builtin_amdgcn_mfma_f32_16x16x32_bf16(af[mt], bw, pacc[mt][nf], 0, 0, 0);
    }
  }
  __syncthreads();   // sa reads complete before T32 overlays it

  // ---- C: transpose + x residual + LN2 -> x1 regs + sm ----
  #pragma unroll
  for (int nf = 0; nf < 2; ++nf) {
    const int col = (wv * 2 + nf) * 16 + lr;
    const float bs = pbias[col];
    #pragma unroll
    for (int mt = 0; mt < 2; ++mt)
      #pragma unroll
      for (int j = 0; j < 4; ++j)
        T32[(mt * 16 + lk * 4 + j) * 132 + col] = pacc[mt][nf][j] + bs;
  }
  __syncthreads();
  const int rl = tid >> 3, q = tid & 7;      // 32 rows x 8 threads/row
  float4 xv[4];
  float sum = 0.f, sq = 0.f;
  {
    const float* xrow = x + (rowbase + rl) * CH;
    #pragma unroll
    for (int i = 0; i < 4; ++i) {
      float4 tv = *(const float4*)&T32[rl * 132 + q * 4 + i * 32];
      const float4 xr = *(const float4*)(xrow + q * 4 + i * 32);
      tv.x += xr.x; tv.y += xr.y; tv.z += xr.z; tv.w += xr.w;
      xv[i] = tv;
      sum += tv.x + tv.y + tv.z + tv.w;
      sq  += tv.x * tv.x + tv.y * tv.y + tv.z * tv.z + tv.w * tv.w;
    }
  }
  sum += __shfl_xor(sum, 1); sq += __shfl_xor(sq, 1);
  sum += __shfl_xor(sum, 2); sq += __shfl_xor(sq, 2);
  sum += __shfl_xor(sum, 4); sq += __shfl_xor(sq, 4);
  {
    const float mean = sum * (1.0f / CH);
    const float inv  = rsqrtf(sq * (1.0f / CH) - mean * mean + 1e-5f);
    #pragma unroll
    for (int i = 0; i < 4; ++i) {
      const int col0 = q * 4 + i * 32;
      const float4 gg = *(const float4*)(g2 + col0);
      const float4 bb = *(const float4*)(b2 + col0);
      const float m0 = (xv[i].x - mean) * inv * gg.x + bb.x;
      const float m1 = (xv[i].y - mean) * inv * gg.y + bb.y;
      const float m2 = (xv[i].z - mean) * inv * gg.z + bb.z;
      const float m3 = (xv[i].w - mean) * inv * gg.w + bb.w;
      const int slot = col0 >> 3;
      const int off = rl * 128 + ((slot ^ (rl & 15)) << 3) + (col0 & 7);
      uint2 pk; pk.x = pack2(m0, m1); pk.y = pack2(m2, m3);
      *(uint2*)&sm[off] = pk;
    }
  }
  __syncthreads();

  // ---- D: MLP (R10-proven), reading sm ----
  f32x4 oad[2][2];
  #pragma unroll
  for (int a = 0; a < 2; ++a) { oad[a][0] = (f32x4){0,0,0,0}; oad[a][1] = (f32x4){0,0,0,0}; }

  auto stage1 = [&](int hb, u16* Hbuf) {
    f32x4 c1[2];
    c1[0] = (f32x4){0.f, 0.f, 0.f, 0.f};
    c1[1] = (f32x4){0.f, 0.f, 0.f, 0.f};
    #pragma unroll
    for (int kk = 0; kk < 4; ++kk) {
      const int c16 = hb * 4 + wv;
      const bf16x8 a1 = *(const bf16x8*)(w1f + ((c16 * 4 + kk) * 64 + lane) * 8);
      bf16x8 bmv[2];
      #pragma unroll
      for (int nt = 0; nt < 2; ++nt) {
        const int r = nt * 16 + lr;
        bmv[nt] = *(const bf16x8*)(sm + r * 128 + (((kk * 4 + lk) ^ (r & 15)) << 3));
      }
      c1[0] = __builtin_amdgcn_mfma_f32_16x16x32_bf16(a1, bmv[0], c1[0], 0, 0, 0);
      c1[1] = __builtin_amdgcn_mfma_f32_16x16x32_bf16(a1, bmv[1], c1[1], 0, 0, 0);
    }
    const int hc0 = wv * 16 + lk * 4;
    const float4 bs = *(const float4*)(b1 + hb * 64 + hc0);
    #pragma unroll
    for (int nt = 0; nt < 2; ++nt) {
      const int tok = nt * 16 + lr;
      uint2 pk2;
      pk2.x = pack2(gelu(c1[nt][0] + bs.x), gelu(c1[nt][1] + bs.y));
      pk2.y = pack2(gelu(c1[nt][2] + bs.z), gelu(c1[nt][3] + bs.w));
      *(uint2*)&Hbuf[tok * HS + hc0] = pk2;
    }
  };

  auto stage2 = [&](int hb, const u16* Hbuf) {
    #pragma unroll
    for (int kk2 = 0; kk2 < 2; ++kk2) {
      bf16x8 a2[2];
      #pragma unroll
      for (int mt = 0; mt < 2; ++mt) {
        const u16* pr = &Hbuf[(mt * 16 + lr) * HS + kk2 * 32 + lk * 8];
        const bf16x4 lo = *(const bf16x4*)pr;
        const bf16x4 hi = *(const bf16x4*)(pr + 4);
        a2[mt] = __builtin_shufflevector(lo, hi, 0, 1, 2, 3, 4, 5, 6, 7);
      }
      #pragma unroll
      for (int nf2 = 0; nf2 < 2; ++nf2) {
        const int o16 = wv * 2 + nf2;
        const bf16x8 bw = *(const bf16x8*)(w2f + (((o16 * 8 + hb) * 2 + kk2) * 64 + lane) * 8);
        #pragma unroll
        for (int mt = 0; mt < 2; ++mt)
          oad[mt][nf2] = __builtin_amdgcn_mfma_f32_16x16x32_bf16(a2[mt], bw, oad[mt][nf2], 0, 0, 0);
      }
    }
  };

  u16* H0 = H;
  u16* H1 = H + 32 * HS;
  stage1(0, H0);
  __syncthreads();
  for (int hb = 0; hb < 8; ++hb) {
    u16* cur = (hb & 1) ? H1 : H0;
    u16* nxt = (hb & 1) ? H0 : H1;
    if (hb < 7) stage1(hb + 1, nxt);
    stage2(hb, cur);
    __syncthreads();
  }

  // ---- E: transpose + fc2 bias, then + x1 regs -> out ----
  #pragma unroll
  for (int nf2 = 0; nf2 < 2; ++nf2) {
    const int col = wv * 32 + nf2 * 16 + lr;
    const float bs = fc2b[col];
    #pragma unroll
    for (int mt = 0; mt < 2; ++mt)
      #pragma unroll
      for (int j = 0; j < 4; ++j)
        T32[(mt * 16 + lk * 4 + j) * 132 + col] = oad[mt][nf2][j] + bs;
  }
  __syncthreads();
  {
    float* orow = outp + (rowbase + rl) * CH;
    #pragma unroll
    for (int i = 0; i < 4; ++i) {
      float4 v = *(const float4*)&T32[rl * 132 + q * 4 + i * 32];
      v.x += xv[i].x; v.y += xv[i].y; v.z += xv[i].z; v.w += xv[i].w;
      *(float4*)(orow + q * 4 + i * 32) = v;
    }
  }
}

// ---------------------------------------------------------------------------
extern "C" void kernel_launch(void* const* d_in, const int* in_sizes, int n_in,
                              void* d_out, int out_size, void* d_ws, size_t ws_size,
                              hipStream_t stream)
{
  const float* x       = (const float*)d_in[0];
  const float* prompts = (const float*)d_in[1];
  const float* n1g     = (const float*)d_in[2];
  const float* n1b     = (const float*)d_in[3];
  const float* qkv_w   = (const float*)d_in[4];
  const float* qkv_b   = (const float*)d_in[5];
  const float* qkv_la  = (const float*)d_in[6];
  const float* qkv_lb  = (const float*)d_in[7];
  const float* rpb     = (const float*)d_in[8];
  const float* proj_w  = (const float*)d_in[9];
  const float* proj_b  = (const float*)d_in[10];
  const float* proj_la = (const float*)d_in[11];
  const float* proj_lb = (const float*)d_in[12];
  const float* n2g     = (const float*)d_in[13];
  const float* n2b     = (const float*)d_in[14];
  const float* fc1_w   = (const float*)d_in[15];
  const float* fc1_b   = (const float*)d_in[16];
  const float* fc1_la  = (const float*)d_in[17];
  const float* fc1_lb  = (const float*)d_in[18];
  const float* fc2_w   = (const float*)d_in[19];
  const float* fc2_b   = (const float*)d_in[20];
  const float* fc2_la  = (const float*)d_in[21];
  const float* fc2_lb  = (const float*)d_in[22];

  // workspace: [wqf|wprojf|w1f|w2f = 196608 u16] [bm 65536 f32] | aobuf
  char* ws = (char*)d_ws;
  u16* wT     = (u16*)ws;
  u16* wqf    = wT;
  u16* wprojf = wT + 49152;
  u16* w1f    = wT + 65536;
  u16* w2f    = wT + 131072;
  float* bm   = (float*)(ws + 393216);
  u16* aobuf  = (u16*)(ws + 393216 + 262144);

  fuse_all_kernel<<<768, 256, 0, stream>>>(
      qkv_w, qkv_la, qkv_lb, proj_w, proj_la, proj_lb,
      fc1_w, fc1_la, fc1_lb, fc2_w, fc2_la, fc2_lb, wT);

  bm_kernel<<<256, 256, 0, stream>>>(rpb, bm);

  qkv_attn_kernel<<<BWIN, 256, 0, stream>>>(
      x, prompts, n1g, n1b, wqf, qkv_b, bm, aobuf);

  proj_mlp_kernel<<<MPIX / 32, 256, 0, stream>>>(
      aobuf, wprojf, proj_b, x, n2g, n2b,
      w1f, fc1_b, w2f, fc2_b, (float*)d_out);
}

// Round 17
// 148.405 us; speedup vs baseline: 1.4728x; 1.0419x over previous
//
#include <hip/hip_runtime.h>
#include <hip/hip_bf16.h>

typedef unsigned short u16;
typedef unsigned int   u32;
typedef short bf16x8 __attribute__((ext_vector_type(8)));
typedef short bf16x4 __attribute__((ext_vector_type(4)));
typedef float f32x4  __attribute__((ext_vector_type(4)));

#define HIMG 56
#define WIMG 56
#define CH   128
#define NHEADS 4
#define WSZ  7
#define SSH  3
#define PP   10
#define HIDD 512
#define NWIN 49          // window tokens
#define NTOK 59          // P + NWIN
#define BWIN 2048        // B * NW
#define DH   32          // head dim
#define MPIX 100352      // B * 56 * 56

// pack two f32 -> two bf16 (RTNE) via v_cvt_pk_bf16_f32
__device__ __forceinline__ u32 pack2(float a, float b) {
  union { __hip_bfloat162 h; u32 u; } cv;
  cv.h = __float22bfloat162_rn(make_float2(a, b));
  return cv.u;
}
__device__ __forceinline__ u16 f2b(float f) {
  u32 u = __float_as_uint(f);
  u += 0x7fffu + ((u >> 16) & 1u);
  return (u16)(u >> 16);
}
// tanh-approx GELU (max err ~3e-4, << bf16 ulp at these magnitudes)
__device__ __forceinline__ float gelu(float x) {
  const float u = x * x;
  const float y = 0.7978845608028654f * x * fmaf(0.044715f, u, 1.0f);
  const float e = __expf(2.0f * y);
  const float th = 1.0f - 2.0f / (e + 1.0f);
  const float s = 0.5f * x;
  return fmaf(s, th, s);
}

// ---------------------------------------------------------------------------
// Fold LoRA into effective weights (MFMA-fragment layouts, R8-proven) AND
// build bias+mask table bm[type][h][64][64] — merged into one dispatch.
// ---------------------------------------------------------------------------
__global__ void setup_kernel(
    const float* __restrict__ qw,  const float* __restrict__ qa,  const float* __restrict__ qb,
    const float* __restrict__ pw,  const float* __restrict__ pa,  const float* __restrict__ pb,
    const float* __restrict__ f1w, const float* __restrict__ f1a, const float* __restrict__ f1b,
    const float* __restrict__ f2w, const float* __restrict__ f2a, const float* __restrict__ f2b2,
    const float* __restrict__ rpb,
    u16* __restrict__ out, float* __restrict__ bm)
{
  const int blk = blockIdx.x;
  if (blk >= 768) {
    // ---- bm table: 256 blocks ----
    const int idx = (blk - 768) * 256 + threadIdx.x;   // 65536
    const int j = idx & 63, i = (idx >> 6) & 63, h = (idx >> 12) & 3, type = idx >> 14;
    float v = 0.f;
    if (i < 49) {
      if (j >= 59) v = -1e30f;
      else if (j >= PP) {
        const int jw = j - PP;
        const int ih = i / 7, iw = i - ih * 7, jh = jw / 7, jw2 = jw - jh * 7;
        v = rpb[((ih - jh + 6) * 13 + (iw - jw2 + 6)) * NHEADS + h];
        const int wh7 = type >> 1, ww7 = type & 1;
        const int mi = 3 * (wh7 ? (ih < 4 ? 1 : 2) : 0) + (ww7 ? (iw < 4 ? 1 : 2) : 0);
        const int mj = 3 * (wh7 ? (jh < 4 ? 1 : 2) : 0) + (ww7 ? (jw2 < 4 ? 1 : 2) : 0);
        if (mi != mj) v -= 100.f;
      }
    }
    bm[idx] = v;
    return;
  }
  const int idx = blk * 256 + threadIdx.x;
  int n, k, Nc;
  const float *w, *la, *lb;
  if (idx < 49152) {                    // wqf
    const int li = idx;
    const int j = li & 7, lane = (li >> 3) & 63, kk = (li >> 9) & 3, c16 = li >> 11;
    n = c16 * 16 + (lane & 15);
    k = kk * 32 + (lane >> 4) * 8 + j;
    w = qw; la = qa; lb = qb; Nc = 384;
  } else if (idx < 65536) {             // wprojf
    const int li = idx - 49152;
    const int j = li & 7, lane = (li >> 3) & 63, kk = (li >> 9) & 3, c16 = li >> 11;
    n = c16 * 16 + (lane & 15);
    k = kk * 32 + (lane >> 4) * 8 + j;
    w = pw; la = pa; lb = pb; Nc = 128;
  } else if (idx < 131072) {            // w1f
    const int li = idx - 65536;
    const int j = li & 7, lane = (li >> 3) & 63, kk = (li >> 9) & 3, c16 = li >> 11;
    n = c16 * 16 + (lane & 15);
    k = kk * 32 + (lane >> 4) * 8 + j;
    w = f1w; la = f1a; lb = f1b; Nc = 512;
  } else {                              // w2f
    const int li = idx - 131072;
    const int j = li & 7, lane = (li >> 3) & 63, kk2 = (li >> 9) & 1, hb = (li >> 10) & 7, o16 = li >> 13;
    n = o16 * 16 + (lane & 15);
    k = hb * 64 + kk2 * 32 + (lane >> 4) * 8 + j;
    w = f2w; la = f2a; lb = f2b2; Nc = 128;
  }
  float s = w[k * Nc + n];
  #pragma unroll
  for (int r = 0; r < 4; ++r) s += la[k * 4 + r] * lb[r * Nc + n];
  out[idx] = f2b(s);
}

// ---------------------------------------------------------------------------
// FUSED LN1 + qkv GEMM + window attention (R15/R16-proven structure).
// ---------------------------------------------------------------------------
#define QKS 136
#define VTS 72
#define PS  68
__global__ __launch_bounds__(256, 3) void qkv_attn_kernel(
    const float* __restrict__ x, const float* __restrict__ prompts,
    const float* __restrict__ n1g, const float* __restrict__ n1b,
    const u16* __restrict__ wqf, const float* __restrict__ qbias,
    const float* __restrict__ bm, u16* __restrict__ attn_out)
{
  __shared__ __align__(16) u16 smem[26624];   // 53248 B -> 3 blocks/CU
  u16* q_lds = smem;                // [64][QKS]
  u16* k_lds = smem + 64 * QKS;     // [64][QKS]
  u16* vt    = smem + 128 * QKS;    // [128][VTS]  (phase 0: t_lds overlay)
  u16* p_lds = smem;                // overlay q+k: [4][64][PS]
  char* t_lds = (char*)vt;          // [64] rows x 256 B, 16B-slot XOR swizzle

  const int tid = threadIdx.x;
  const int wv = tid >> 6, lane = tid & 63;
  const int lr = lane & 15, lk = lane >> 4;
  const int b_ = blockIdx.x;
  const int bimg = b_ >> 6;
  const int wwin = b_ & 63;

  // ---- phase 0: LN1 + roll + window gather -> t_lds ----
  {
    const float2 gg = *(const float2*)(n1g + lane * 2);
    const float2 bv = *(const float2*)(n1b + lane * 2);
    for (int it = 0; it < 16; ++it) {
      const int n = wv * 16 + it;
      if (n >= NTOK) break;                       // uniform per wave
      const float* src;
      if (n < PP) {
        src = prompts + ((size_t)bimg * PP + n) * CH;
      } else {
        const int wi = n - PP;
        const int hr = (wwin >> 3) * WSZ + wi / WSZ;
        const int wc = (wwin & 7) * WSZ + wi % WSZ;
        const int hs = (hr + SSH) % HIMG;
        const int ws2 = (wc + SSH) % WIMG;
        src = x + ((size_t)bimg * (HIMG * WIMG) + hs * WIMG + ws2) * CH;
      }
      const float2 v = *(const float2*)(src + lane * 2);
      u32 pk;
      if (n < PP) {
        pk = pack2(v.x, v.y);
      } else {
        float s = v.x + v.y, s2 = v.x * v.x + v.y * v.y;
        #pragma unroll
        for (int o = 32; o > 0; o >>= 1) { s += __shfl_xor(s, o); s2 += __shfl_xor(s2, o); }
        const float mean = s * (1.0f / CH);
        const float inv  = rsqrtf(s2 * (1.0f / CH) - mean * mean + 1e-5f);
        pk = pack2((v.x - mean) * inv * gg.x + bv.x, (v.y - mean) * inv * gg.y + bv.y);
      }
      const int slot = (lane >> 2) ^ (n & 7);
      *(u32*)(t_lds + n * 256 + slot * 16 + (lane & 3) * 4) = pk;
    }
  }
  __syncthreads();

  // ---- af frags from t_lds (swizzled slots) ----
  bf16x8 af[4][4];
  #pragma unroll
  for (int mt = 0; mt < 4; ++mt) {
    int tok = mt * 16 + lr; if (tok > 58) tok = 58;
    #pragma unroll
    for (int kk = 0; kk < 4; ++kk) {
      const int slot = (kk * 4 + lk) ^ (tok & 7);
      af[mt][kk] = *(const bf16x8*)(t_lds + tok * 256 + slot * 16);
    }
  }
  __syncthreads();   // all t_lds reads done before vt writes overlay it

  // ---- phase 1: qkv ----
  #pragma unroll
  for (int nf = 0; nf < 6; ++nf) {
    const int c = wv * 96 + nf * 16 + lr;
    const int sel = wv * 6 + nf;
    bf16x8 bw[4];
    #pragma unroll
    for (int kk = 0; kk < 4; ++kk)
      bw[kk] = *(const bf16x8*)(wqf + ((sel * 4 + kk) * 64 + lane) * 8);
    f32x4 a4[4];
    #pragma unroll
    for (int mt = 0; mt < 4; ++mt) a4[mt] = (f32x4){0.f, 0.f, 0.f, 0.f};
    #pragma unroll
    for (int kk = 0; kk < 4; ++kk)
      #pragma unroll
      for (int mt = 0; mt < 4; ++mt)
        a4[mt] = __builtin_amdgcn_mfma_f32_16x16x32_bf16(af[mt][kk], bw[kk], a4[mt], 0, 0, 0);
    const float bs = qbias[c];
    #pragma unroll
    for (int mt = 0; mt < 4; ++mt) {
      const int tok0 = mt * 16 + lk * 4;
      if (sel < 8) {
        #pragma unroll
        for (int rg = 0; rg < 4; rg += 2) {
          const u32 pk = pack2(a4[mt][rg] + bs, a4[mt][rg + 1] + bs);
          q_lds[(tok0 + rg) * QKS + c]     = (u16)pk;
          q_lds[(tok0 + rg + 1) * QKS + c] = (u16)(pk >> 16);
        }
      } else if (sel < 16) {
        #pragma unroll
        for (int rg = 0; rg < 4; rg += 2) {
          const u32 pk = pack2(a4[mt][rg] + bs, a4[mt][rg + 1] + bs);
          k_lds[(tok0 + rg) * QKS + (c - 128)]     = (u16)pk;
          k_lds[(tok0 + rg + 1) * QKS + (c - 128)] = (u16)(pk >> 16);
        }
      } else {
        uint2 pk2;
        pk2.x = pack2(a4[mt][0] + bs, a4[mt][1] + bs);
        pk2.y = pack2(a4[mt][2] + bs, a4[mt][3] + bs);
        *(uint2*)&vt[(c - 256) * VTS + tok0] = pk2;
      }
    }
  }
  __syncthreads();

  // ---- phase 2: attention, wave = head h ----
  const int h = wv;
  const int type = (((wwin >> 3) == 7) ? 2 : 0) + (((wwin & 7) == 7) ? 1 : 0);
  const float scale = 0.17677669529663687f;

  bf16x8 kf[4], qf[4];
  #pragma unroll
  for (int t4 = 0; t4 < 4; ++t4) {
    kf[t4] = *(const bf16x8*)&k_lds[(t4 * 16 + lr) * QKS + h * DH + lk * 8];
    int tq = PP + t4 * 16 + lr; if (tq > 63) tq = 63;
    qf[t4] = *(const bf16x8*)&q_lds[tq * QKS + h * DH + lk * 8];
  }
  f32x4 sacc[4][4];
  #pragma unroll
  for (int a = 0; a < 4; ++a)
    #pragma unroll
    for (int b = 0; b < 4; ++b)
      sacc[a][b] = (f32x4){0.f, 0.f, 0.f, 0.f};
  #pragma unroll
  for (int mtj = 0; mtj < 4; ++mtj)
    #pragma unroll
    for (int nti = 0; nti < 4; ++nti)
      sacc[mtj][nti] = __builtin_amdgcn_mfma_f32_16x16x32_bf16(kf[mtj], qf[nti], sacc[mtj][nti], 0, 0, 0);

  const float* bmh = bm + (size_t)(type * NHEADS + h) * 64 * 64;
  #pragma unroll
  for (int nti = 0; nti < 4; ++nti) {
    const int i = nti * 16 + lr;
    float sv[16];
    #pragma unroll
    for (int mtj = 0; mtj < 4; ++mtj) {
      const float4 bmv = *(const float4*)(bmh + i * 64 + mtj * 16 + lk * 4);
      sv[mtj * 4 + 0] = sacc[mtj][nti][0] * scale + bmv.x;
      sv[mtj * 4 + 1] = sacc[mtj][nti][1] * scale + bmv.y;
      sv[mtj * 4 + 2] = sacc[mtj][nti][2] * scale + bmv.z;
      sv[mtj * 4 + 3] = sacc[mtj][nti][3] * scale + bmv.w;
    }
    float mx = sv[0];
    #pragma unroll
    for (int q = 1; q < 16; ++q) mx = fmaxf(mx, sv[q]);
    mx = fmaxf(mx, __shfl_xor(mx, 16));
    mx = fmaxf(mx, __shfl_xor(mx, 32));
    float sum = 0.f;
    #pragma unroll
    for (int q = 0; q < 16; ++q) { sv[q] = __expf(sv[q] - mx); sum += sv[q]; }
    sum += __shfl_xor(sum, 16);
    sum += __shfl_xor(sum, 32);
    const float inv = 1.0f / sum;
    #pragma unroll
    for (int mtj = 0; mtj < 4; ++mtj) {
      sacc[mtj][nti][0] = sv[mtj * 4 + 0] * inv;
      sacc[mtj][nti][1] = sv[mtj * 4 + 1] * inv;
      sacc[mtj][nti][2] = sv[mtj * 4 + 2] * inv;
      sacc[mtj][nti][3] = sv[mtj * 4 + 3] * inv;
    }
  }
  __syncthreads();

  u16* ph = p_lds + h * 64 * PS;
  #pragma unroll
  for (int nti = 0; nti < 4; ++nti) {
    const int i = nti * 16 + lr;
    #pragma unroll
    for (int mtj = 0; mtj < 4; ++mtj) {
      uint2 pk2;
      pk2.x = pack2(sacc[mtj][nti][0], sacc[mtj][nti][1]);
      pk2.y = pack2(sacc[mtj][nti][2], sacc[mtj][nti][3]);
      *(uint2*)&ph[i * PS + mtj * 16 + lk * 4] = pk2;
    }
  }
  __syncthreads();

  f32x4 oacc[4][2];
  #pragma unroll
  for (int a = 0; a < 4; ++a) { oacc[a][0] = (f32x4){0,0,0,0}; oacc[a][1] = (f32x4){0,0,0,0}; }
  #pragma unroll
  for (int ks = 0; ks < 2; ++ks) {
    bf16x8 pa[4];
    #pragma unroll
    for (int mt = 0; mt < 4; ++mt) {
      const u16* pr = &ph[(mt * 16 + lr) * PS + ks * 32 + lk * 8];
      const bf16x4 lo = *(const bf16x4*)pr;
      const bf16x4 hi = *(const bf16x4*)(pr + 4);
      pa[mt] = __builtin_shufflevector(lo, hi, 0, 1, 2, 3, 4, 5, 6, 7);
    }
    bf16x8 bv[2];
    #pragma unroll
    for (int nd = 0; nd < 2; ++nd)
      bv[nd] = *(const bf16x8*)&vt[(h * DH + nd * 16 + lr) * VTS + ks * 32 + lk * 8];
    #pragma unroll
    for (int mt = 0; mt < 4; ++mt)
      #pragma unroll
      for (int nd = 0; nd < 2; ++nd)
        oacc[mt][nd] = __builtin_amdgcn_mfma_f32_16x16x32_bf16(pa[mt], bv[nd], oacc[mt][nd], 0, 0, 0);
  }

  #pragma unroll
  for (int mt = 0; mt < 4; ++mt)
    #pragma unroll
    for (int rg = 0; rg < 4; ++rg) {
      const int i = mt * 16 + lk * 4 + rg;
      const u32 pk = pack2(oacc[mt][0][rg], oacc[mt][1][rg]);
      ph[i * PS + lr]      = (u16)pk;
      ph[i * PS + 16 + lr] = (u16)(pk >> 16);
    }
  __syncthreads();
  if (lane < NWIN) {
    const u16* src = &ph[lane * PS];
    u16* dst = attn_out + ((size_t)b_ * NWIN + lane) * CH + h * DH;
    #pragma unroll
    for (int c = 0; c < 8; ++c)
      *(uint2*)(dst + c * 4) = *(const uint2*)(src + c * 4);
  }
}

// ---------------------------------------------------------------------------
// FUSED proj + LN2 + MLP (R11/R15/R16-proven: 33792B LDS, 4 blocks/CU).
// ---------------------------------------------------------------------------
#define HS 68
__global__ __launch_bounds__(256, 4) void proj_mlp_kernel(
    const u16* __restrict__ ao, const u16* __restrict__ wprojf,
    const float* __restrict__ pbias, const float* __restrict__ x,
    const float* __restrict__ g2, const float* __restrict__ b2,
    const u16* __restrict__ w1f, const float* __restrict__ b1,
    const u16* __restrict__ w2f, const float* __restrict__ fc2b,
    float* __restrict__ outp)
{
  __shared__ __align__(16) char smem[33792];
  u16*   sa  = (u16*)smem;              // [32][128] gathered ao tile
  float* T32 = (float*)smem;            // [32][132] transpose buffer
  u16*   sm  = (u16*)(smem + 16896);    // [32][128] m tile, swizzle16
  u16*   H   = (u16*)(smem + 25088);    // [2][32][HS]
  const int tid = threadIdx.x;
  const int wv = tid >> 6, lane = tid & 63;
  const int lr = lane & 15, lk = lane >> 4;
  const long rowbase = (long)blockIdx.x * 32;

  // ---- A: gather ao rows (inverse window map), swizzle16 source ----
  #pragma unroll
  for (int it = 0; it < 2; ++it) {
    const int c = it * 256 + tid;
    const int r = c >> 4, s = c & 15;
    const int k8 = s ^ (r & 15);
    const int pix = (int)rowbase + r;
    const int b  = pix / 3136;
    const int rem = pix - b * 3136;
    const int hf = rem / 56, wf = rem - hf * 56;
    int hs = hf + 53; if (hs >= 56) hs -= 56;
    int ws2 = wf + 53; if (ws2 >= 56) ws2 -= 56;
    const int w  = (hs / 7) * 8 + (ws2 / 7);
    const int wi = (hs % 7) * 7 + (ws2 % 7);
    const long arow = ((long)b * 64 + w) * NWIN + wi;
    __builtin_amdgcn_global_load_lds((const void*)(ao + arow * CH + k8 * 8),
                                     (void*)(sa + c * 8), 16, 0, 0);
  }
  __syncthreads();

  // ---- B: proj MFMA ----
  f32x4 pacc[2][2];
  #pragma unroll
  for (int a = 0; a < 2; ++a) { pacc[a][0] = (f32x4){0,0,0,0}; pacc[a][1] = (f32x4){0,0,0,0}; }
  #pragma unroll
  for (int kk = 0; kk < 4; ++kk) {
    bf16x8 af[2];
    #pragma unroll
    for (int mt = 0; mt < 2; ++mt) {
      const int r = mt * 16 + lr;
      af[mt] = *(const bf16x8*)(sa + r * 128 + (((kk * 4 + lk) ^ (r & 15)) << 3));
    }
    #pragma unroll
    for (int nf = 0; nf < 2; ++nf) {
      const int c16 = wv * 2 + nf;
      const bf16x8 bw = *(const bf16x8*)(wprojf + ((c16 * 4 + kk) * 64 + lane) * 8);
      #pragma unroll
      for (int mt = 0; mt < 2; ++mt)
        pacc[mt][nf] = __builtin_amdgcn_mfma_f32_16x16x32_bf16(af[mt], bw, pacc[mt][nf], 0, 0, 0);
    }
  }
  __syncthreads();   // sa reads complete before T32 overlays it

  // ---- C: transpose + x residual + LN2 -> x1 regs + sm ----
  #pragma unroll
  for (int nf = 0; nf < 2; ++nf) {
    const int col = (wv * 2 + nf) * 16 + lr;
    const float bs = pbias[col];
    #pragma unroll
    for (int mt = 0; mt < 2; ++mt)
      #pragma unroll
      for (int j = 0; j < 4; ++j)
        T32[(mt * 16 + lk * 4 + j) * 132 + col] = pacc[mt][nf][j] + bs;
  }
  __syncthreads();
  const int rl = tid >> 3, q = tid & 7;      // 32 rows x 8 threads/row
  float4 xv[4];
  float sum = 0.f, sq = 0.f;
  {
    const float* xrow = x + (rowbase + rl) * CH;
    #pragma unroll
    for (int i = 0; i < 4; ++i) {
      float4 tv = *(const float4*)&T32[rl * 132 + q * 4 + i * 32];
      const float4 xr = *(const float4*)(xrow + q * 4 + i * 32);
      tv.x += xr.x; tv.y += xr.y; tv.z += xr.z; tv.w += xr.w;
      xv[i] = tv;
      sum += tv.x + tv.y + tv.z + tv.w;
      sq  += tv.x * tv.x + tv.y * tv.y + tv.z * tv.z + tv.w * tv.w;
    }
  }
  sum += __shfl_xor(sum, 1); sq += __shfl_xor(sq, 1);
  sum += __shfl_xor(sum, 2); sq += __shfl_xor(sq, 2);
  sum += __shfl_xor(sum, 4); sq += __shfl_xor(sq, 4);
  {
    const float mean = sum * (1.0f / CH);
    const float inv  = rsqrtf(sq * (1.0f / CH) - mean * mean + 1e-5f);
    #pragma unroll
    for (int i = 0; i < 4; ++i) {
      const int col0 = q * 4 + i * 32;
      const float4 gg = *(const float4*)(g2 + col0);
      const float4 bb = *(const float4*)(b2 + col0);
      const float m0 = (xv[i].x - mean) * inv * gg.x + bb.x;
      const float m1 = (xv[i].y - mean) * inv * gg.y + bb.y;
      const float m2 = (xv[i].z - mean) * inv * gg.z + bb.z;
      const float m3 = (xv[i].w - mean) * inv * gg.w + bb.w;
      const int slot = col0 >> 3;
      const int off = rl * 128 + ((slot ^ (rl & 15)) << 3) + (col0 & 7);
      uint2 pk; pk.x = pack2(m0, m1); pk.y = pack2(m2, m3);
      *(uint2*)&sm[off] = pk;
    }
  }
  __syncthreads();

  // ---- D: MLP (R10-proven), reading sm ----
  f32x4 oad[2][2];
  #pragma unroll
  for (int a = 0; a < 2; ++a) { oad[a][0] = (f32x4){0,0,0,0}; oad[a][1] = (f32x4){0,0,0,0}; }

  auto stage1 = [&](int hb, u16* Hbuf) {
    f32x4 c1[2];
    c1[0] = (f32x4){0.f, 0.f, 0.f, 0.f};
    c1[1] = (f32x4){0.f, 0.f, 0.f, 0.f};
    #pragma unroll
    for (int kk = 0; kk < 4; ++kk) {
      const int c16 = hb * 4 + wv;
      const bf16x8 a1 = *(const bf16x8*)(w1f + ((c16 * 4 + kk) * 64 + lane) * 8);
      bf16x8 bmv[2];
      #pragma unroll
      for (int nt = 0; nt < 2; ++nt) {
        const int r = nt * 16 + lr;
        bmv[nt] = *(const bf16x8*)(sm + r * 128 + (((kk * 4 + lk) ^ (r & 15)) << 3));
      }
      c1[0] = __builtin_amdgcn_mfma_f32_16x16x32_bf16(a1, bmv[0], c1[0], 0, 0, 0);
      c1[1] = __builtin_amdgcn_mfma_f32_16x16x32_bf16(a1, bmv[1], c1[1], 0, 0, 0);
    }
    const int hc0 = wv * 16 + lk * 4;
    const float4 bs = *(const float4*)(b1 + hb * 64 + hc0);
    #pragma unroll
    for (int nt = 0; nt < 2; ++nt) {
      const int tok = nt * 16 + lr;
      uint2 pk2;
      pk2.x = pack2(gelu(c1[nt][0] + bs.x), gelu(c1[nt][1] + bs.y));
      pk2.y = pack2(gelu(c1[nt][2] + bs.z), gelu(c1[nt][3] + bs.w));
      *(uint2*)&Hbuf[tok * HS + hc0] = pk2;
    }
  };

  auto stage2 = [&](int hb, const u16* Hbuf) {
    #pragma unroll
    for (int kk2 = 0; kk2 < 2; ++kk2) {
      bf16x8 a2[2];
      #pragma unroll
      for (int mt = 0; mt < 2; ++mt) {
        const u16* pr = &Hbuf[(mt * 16 + lr) * HS + kk2 * 32 + lk * 8];
        const bf16x4 lo = *(const bf16x4*)pr;
        const bf16x4 hi = *(const bf16x4*)(pr + 4);
        a2[mt] = __builtin_shufflevector(lo, hi, 0, 1, 2, 3, 4, 5, 6, 7);
      }
      #pragma unroll
      for (int nf2 = 0; nf2 < 2; ++nf2) {
        const int o16 = wv * 2 + nf2;
        const bf16x8 bw = *(const bf16x8*)(w2f + (((o16 * 8 + hb) * 2 + kk2) * 64 + lane) * 8);
        #pragma unroll
        for (int mt = 0; mt < 2; ++mt)
          oad[mt][nf2] = __builtin_amdgcn_mfma_f32_16x16x32_bf16(a2[mt], bw, oad[mt][nf2], 0, 0, 0);
      }
    }
  };

  u16* H0 = H;
  u16* H1 = H + 32 * HS;
  stage1(0, H0);
  __syncthreads();
  for (int hb = 0; hb < 8; ++hb) {
    u16* cur = (hb & 1) ? H1 : H0;
    u16* nxt = (hb & 1) ? H0 : H1;
    if (hb < 7) stage1(hb + 1, nxt);
    stage2(hb, cur);
    __syncthreads();
  }

  // ---- E: transpose + fc2 bias, then + x1 regs -> out ----
  #pragma unroll
  for (int nf2 = 0; nf2 < 2; ++nf2) {
    const int col = wv * 32 + nf2 * 16 + lr;
    const float bs = fc2b[col];
    #pragma unroll
    for (int mt = 0; mt < 2; ++mt)
      #pragma unroll
      for (int j = 0; j < 4; ++j)
        T32[(mt * 16 + lk * 4 + j) * 132 + col] = oad[mt][nf2][j] + bs;
  }
  __syncthreads();
  {
    float* orow = outp + (rowbase + rl) * CH;
    #pragma unroll
    for (int i = 0; i < 4; ++i) {
      float4 v = *(const float4*)&T32[rl * 132 + q * 4 + i * 32];
      v.x += xv[i].x; v.y += xv[i].y; v.z += xv[i].z; v.w += xv[i].w;
      *(float4*)(orow + q * 4 + i * 32) = v;
    }
  }
}

// ---------------------------------------------------------------------------
extern "C" void kernel_launch(void* const* d_in, const int* in_sizes, int n_in,
                              void* d_out, int out_size, void* d_ws, size_t ws_size,
                              hipStream_t stream)
{
  const float* x       = (const float*)d_in[0];
  const float* prompts = (const float*)d_in[1];
  const float* n1g     = (const float*)d_in[2];
  const float* n1b     = (const float*)d_in[3];
  const float* qkv_w   = (const float*)d_in[4];
  const float* qkv_b   = (const float*)d_in[5];
  const float* qkv_la  = (const float*)d_in[6];
  const float* qkv_lb  = (const float*)d_in[7];
  const float* rpb     = (const float*)d_in[8];
  const float* proj_w  = (const float*)d_in[9];
  const float* proj_b  = (const float*)d_in[10];
  const float* proj_la = (const float*)d_in[11];
  const float* proj_lb = (const float*)d_in[12];
  const float* n2g     = (const float*)d_in[13];
  const float* n2b     = (const float*)d_in[14];
  const float* fc1_w   = (const float*)d_in[15];
  const float* fc1_b   = (const float*)d_in[16];
  const float* fc1_la  = (const float*)d_in[17];
  const float* fc1_lb  = (const float*)d_in[18];
  const float* fc2_w   = (const float*)d_in[19];
  const float* fc2_b   = (const float*)d_in[20];
  const float* fc2_la  = (const float*)d_in[21];
  const float* fc2_lb  = (const float*)d_in[22];

  // workspace: [wqf|wprojf|w1f|w2f = 196608 u16] [bm 65536 f32] | aobuf
  char* ws = (char*)d_ws;
  u16* wT     = (u16*)ws;
  u16* wqf    = wT;
  u16* wprojf = wT + 49152;
  u16* w1f    = wT + 65536;
  u16* w2f    = wT + 131072;
  float* bm   = (float*)(ws + 393216);
  u16* aobuf  = (u16*)(ws + 393216 + 262144);

  setup_kernel<<<1024, 256, 0, stream>>>(
      qkv_w, qkv_la, qkv_lb, proj_w, proj_la, proj_lb,
      fc1_w, fc1_la, fc1_lb, fc2_w, fc2_la, fc2_lb, rpb, wT, bm);

  qkv_attn_kernel<<<BWIN, 256, 0, stream>>>(
      x, prompts, n1g, n1b, wqf, qkv_b, bm, aobuf);

  proj_mlp_kernel<<<MPIX / 32, 256, 0, stream>>>(
      aobuf, wprojf, proj_b, x, n2g, n2b,
      w1f, fc1_b, w2f, fc2_b, (float*)d_out);
}